// Round 1
// baseline (688.012 us; speedup 1.0000x reference)
//
#include <hip/hip_runtime.h>
#include <hip/hip_bf16.h>
#include <cstdint>

#define T_SEQ   2048
#define DM      512
#define NH      8
#define DH      64
#define BATCH   2
#define MROWS   4096   // B*T
#define DFF     2048
#define CHUNK   64
#define NCHUNK  32     // T/CHUNK
#define BHN     16     // B*H
#define ST_STRIDE 4160 // 64*64 + 64

// ---------------- LayerNorm: one block per row (512 floats) ----------------
__global__ __launch_bounds__(128) void ln_kernel(
    const float* __restrict__ x, const float* __restrict__ g,
    const float* __restrict__ b, float* __restrict__ y)
{
    int row = blockIdx.x;
    int t = threadIdx.x;                       // 128 threads * float4 = 512
    const float4* xr = (const float4*)(x + (size_t)row * DM);
    float4 v = xr[t];
    float s  = v.x + v.y + v.z + v.w;
    float s2 = v.x*v.x + v.y*v.y + v.z*v.z + v.w*v.w;
#pragma unroll
    for (int off = 32; off > 0; off >>= 1) {
        s  += __shfl_down(s,  off);
        s2 += __shfl_down(s2, off);
    }
    __shared__ float sh[4];
    if ((t & 63) == 0) { sh[(t >> 6) * 2] = s; sh[(t >> 6) * 2 + 1] = s2; }
    __syncthreads();
    s  = sh[0] + sh[2];
    s2 = sh[1] + sh[3];
    float mu  = s * (1.0f / DM);
    float var = s2 * (1.0f / DM) - mu * mu;
    float rs  = rsqrtf(var + 1e-5f);
    float4 gg = ((const float4*)g)[t];
    float4 bb = ((const float4*)b)[t];
    float4 o;
    o.x = (v.x - mu) * rs * gg.x + bb.x;
    o.y = (v.y - mu) * rs * gg.y + bb.y;
    o.z = (v.z - mu) * rs * gg.z + bb.z;
    o.w = (v.w - mu) * rs * gg.w + bb.w;
    ((float4*)(y + (size_t)row * DM))[t] = o;
}

// ---------------- fp32 GEMM: C[M,N] = op(A[M,K] @ B[K,N] + bias) (+res) ----
// OP: 0 none, 1 elu(x)+1, 2 relu.  HEAD: write to (B,H,T,DH) layout.
template<int OP, bool HEAD, bool RESID>
__global__ __launch_bounds__(256) void gemm_k(
    const float* __restrict__ A, const float* __restrict__ Bw,
    const float* __restrict__ bias, const float* __restrict__ res,
    float* __restrict__ C, int M, int N, int K)
{
    __shared__ float As[16][128];   // transposed: As[k][m]
    __shared__ float Bs[16][64];
    const int tid = threadIdx.x;
    const int bm = blockIdx.y * 128;
    const int bn = blockIdx.x * 64;
    const int tx = tid & 15;        // -> 4 n
    const int ty = tid >> 4;        // -> 8 m
    const int arow = tid >> 1;      // 0..127
    const int ak   = (tid & 1) * 8;
    const int brow = tid >> 4;      // 0..15
    const int bcol = (tid & 15) * 4;
    const float* Aptr = A + (size_t)(bm + arow) * K + ak;
    const float* Bptr = Bw + (size_t)brow * N + bn + bcol;

    float acc[8][4];
#pragma unroll
    for (int i = 0; i < 8; i++)
#pragma unroll
        for (int j = 0; j < 4; j++) acc[i][j] = 0.0f;

    for (int k0 = 0; k0 < K; k0 += 16) {
        float4 a0 = *(const float4*)(Aptr + k0);
        float4 a1 = *(const float4*)(Aptr + k0 + 4);
        float4 b0 = *(const float4*)(Bptr + (size_t)k0 * N);
        As[ak+0][arow] = a0.x; As[ak+1][arow] = a0.y;
        As[ak+2][arow] = a0.z; As[ak+3][arow] = a0.w;
        As[ak+4][arow] = a1.x; As[ak+5][arow] = a1.y;
        As[ak+6][arow] = a1.z; As[ak+7][arow] = a1.w;
        *(float4*)&Bs[brow][bcol] = b0;
        __syncthreads();
#pragma unroll
        for (int kk = 0; kk < 16; kk++) {
            float4 av0 = *(const float4*)&As[kk][ty*8];
            float4 av1 = *(const float4*)&As[kk][ty*8+4];
            float4 bv  = *(const float4*)&Bs[kk][tx*4];
            float aa[8] = {av0.x,av0.y,av0.z,av0.w,av1.x,av1.y,av1.z,av1.w};
            float bb4[4] = {bv.x,bv.y,bv.z,bv.w};
#pragma unroll
            for (int i = 0; i < 8; i++)
#pragma unroll
                for (int j = 0; j < 4; j++)
                    acc[i][j] = fmaf(aa[i], bb4[j], acc[i][j]);
        }
        __syncthreads();
    }

    float4 bias4 = *(const float4*)(bias + bn + tx*4);
    float bb4[4] = {bias4.x, bias4.y, bias4.z, bias4.w};
#pragma unroll
    for (int i = 0; i < 8; i++) {
        int m = bm + ty*8 + i;
        int n0 = bn + tx*4;
        float o[4];
#pragma unroll
        for (int j = 0; j < 4; j++) {
            float v = acc[i][j] + bb4[j];
            if (OP == 1) v = v > 0.0f ? v + 1.0f : __expf(v);
            if (OP == 2) v = fmaxf(v, 0.0f);
            o[j] = v;
        }
        if (RESID) {
            float4 rv = *(const float4*)(res + (size_t)m * N + n0);
            o[0] += rv.x; o[1] += rv.y; o[2] += rv.z; o[3] += rv.w;
        }
        float4 ov = make_float4(o[0], o[1], o[2], o[3]);
        if (HEAD) {
            int bb_ = m >> 11;          // batch
            int tt  = m & 2047;         // t
            int hh  = n0 >> 6;          // head
            int dd  = n0 & 63;          // d within head
            *(float4*)(C + ((((size_t)(bb_*NH + hh)) * T_SEQ + tt) << 6) + dd) = ov;
        } else {
            *(float4*)(C + (size_t)m * N + n0) = ov;
        }
    }
}

// ---------------- attention phase 1: per-chunk K^T V and colsum(K) ---------
__global__ __launch_bounds__(256) void attn_chunk_sum(
    const float* __restrict__ Kb, const float* __restrict__ Vb,
    float* __restrict__ St)
{
    int blk = blockIdx.x;                    // bh*32 + ch
    const float* Kp = Kb + (size_t)blk * (CHUNK * DH);
    const float* Vp = Vb + (size_t)blk * (CHUNK * DH);
    float* Sp = St + (size_t)blk * ST_STRIDE;
    __shared__ float Ks[64][64];
    __shared__ float Vs[64][64];
    int tid = threadIdx.x;
#pragma unroll
    for (int i = 0; i < 4; i++) {
        ((float4*)Ks)[tid + i*256] = ((const float4*)Kp)[tid + i*256];
        ((float4*)Vs)[tid + i*256] = ((const float4*)Vp)[tid + i*256];
    }
    __syncthreads();
    int r  = tid >> 2;
    int c0 = (tid & 3) * 16;
    float s[16];
#pragma unroll
    for (int i = 0; i < 16; i++) s[i] = 0.0f;
    for (int t = 0; t < 64; t++) {
        float kv = Ks[t][r];
        const float4* vr = (const float4*)&Vs[t][c0];
        float4 v0 = vr[0], v1 = vr[1], v2 = vr[2], v3 = vr[3];
        s[0]+=kv*v0.x; s[1]+=kv*v0.y; s[2]+=kv*v0.z; s[3]+=kv*v0.w;
        s[4]+=kv*v1.x; s[5]+=kv*v1.y; s[6]+=kv*v1.z; s[7]+=kv*v1.w;
        s[8]+=kv*v2.x; s[9]+=kv*v2.y; s[10]+=kv*v2.z; s[11]+=kv*v2.w;
        s[12]+=kv*v3.x; s[13]+=kv*v3.y; s[14]+=kv*v3.z; s[15]+=kv*v3.w;
    }
#pragma unroll
    for (int i = 0; i < 4; i++) {
        float4 ov = make_float4(s[i*4+0], s[i*4+1], s[i*4+2], s[i*4+3]);
        *(float4*)(Sp + (size_t)r*64 + c0 + i*4) = ov;
    }
    if (tid < 64) {
        float z = 0.0f;
        for (int t = 0; t < 64; t++) z += Ks[t][tid];
        Sp[4096 + tid] = z;
    }
}

// ---------------- attention phase 2: exclusive prefix over chunks ----------
__global__ __launch_bounds__(256) void attn_scan(float* __restrict__ St)
{
    int bh = blockIdx.x;
    float* Sp = St + (size_t)bh * NCHUNK * ST_STRIDE;
    int tid = threadIdx.x;
    float4 run[4];
#pragma unroll
    for (int i = 0; i < 4; i++) run[i] = make_float4(0,0,0,0);
    float rz = 0.0f;
    for (int ch = 0; ch < NCHUNK; ch++) {
        float4* p4 = (float4*)(Sp + (size_t)ch * ST_STRIDE);
#pragma unroll
        for (int i = 0; i < 4; i++) {
            float4 t = p4[tid*4 + i];
            p4[tid*4 + i] = run[i];
            run[i].x += t.x; run[i].y += t.y; run[i].z += t.z; run[i].w += t.w;
        }
        if (tid < 64) {
            float* zp = Sp + (size_t)ch * ST_STRIDE + 4096;
            float t = zp[tid];
            zp[tid] = rz;
            rz += t;
        }
    }
}

// ---------------- attention phase 3: per-chunk output ----------------------
__global__ __launch_bounds__(256) void attn_out_k(
    const float* __restrict__ Qb, const float* __restrict__ Kb,
    const float* __restrict__ Vb, const float* __restrict__ St,
    float* __restrict__ attn)
{
    int blk = blockIdx.x;
    int bh = blk >> 5, ch = blk & 31;
    int b = bh >> 3, h = bh & 7;
    const float* Qp = Qb + (size_t)blk * 4096;
    const float* Kp = Kb + (size_t)blk * 4096;
    const float* Vp = Vb + (size_t)blk * 4096;
    const float* Sp = St + (size_t)blk * ST_STRIDE;
    __shared__ float Qs[64][68];
    __shared__ float Kt[64][68];   // transposed: Kt[d][t]
    __shared__ float Vs[64][68];
    __shared__ float Ss[64][68];
    __shared__ float Amat[64][65];
    __shared__ float zs[64];
    int tid = threadIdx.x;
#pragma unroll
    for (int i = 0; i < 4; i++) {
        int fi = tid + i*256;           // float4 index 0..1023
        int t  = fi >> 4;               // row
        int d4 = (fi & 15) * 4;         // col
        float4 q = ((const float4*)Qp)[fi];
        float4 k = ((const float4*)Kp)[fi];
        float4 v = ((const float4*)Vp)[fi];
        float4 s = ((const float4*)Sp)[fi];
        *(float4*)&Qs[t][d4] = q;
        *(float4*)&Vs[t][d4] = v;
        *(float4*)&Ss[t][d4] = s;
        Kt[d4+0][t] = k.x; Kt[d4+1][t] = k.y; Kt[d4+2][t] = k.z; Kt[d4+3][t] = k.w;
    }
    if (tid < 64) zs[tid] = Sp[4096 + tid];
    __syncthreads();
    int r  = tid >> 2;
    int c0 = (tid & 3) * 16;
    // A[r][c0+i] = Q_r . K_{c0+i}
    float a[16];
#pragma unroll
    for (int i = 0; i < 16; i++) a[i] = 0.0f;
    for (int d = 0; d < 64; d++) {
        float q = Qs[r][d];
        const float4* kr = (const float4*)&Kt[d][c0];
        float4 k0 = kr[0], k1 = kr[1], k2 = kr[2], k3 = kr[3];
        a[0]+=q*k0.x; a[1]+=q*k0.y; a[2]+=q*k0.z; a[3]+=q*k0.w;
        a[4]+=q*k1.x; a[5]+=q*k1.y; a[6]+=q*k1.z; a[7]+=q*k1.w;
        a[8]+=q*k2.x; a[9]+=q*k2.y; a[10]+=q*k2.z; a[11]+=q*k2.w;
        a[12]+=q*k3.x; a[13]+=q*k3.y; a[14]+=q*k3.z; a[15]+=q*k3.w;
    }
#pragma unroll
    for (int i = 0; i < 16; i++) Amat[r][c0+i] = a[i];
    __syncthreads();
    // den = Q.z_prev + cumsum_j<=r A[r][j]
    float den = 0.0f;
    for (int d = 0; d < 64; d++) den += Qs[r][d] * zs[d];
    for (int j = 0; j <= r; j++) den += Amat[r][j];
    den = fmaxf(den, 1e-6f);
    // num = Q @ S_prev + (A masked) @ V
    float num[16];
#pragma unroll
    for (int i = 0; i < 16; i++) num[i] = 0.0f;
    for (int d = 0; d < 64; d++) {
        float q = Qs[r][d];
        const float4* sv = (const float4*)&Ss[d][c0];
        float4 s0 = sv[0], s1 = sv[1], s2 = sv[2], s3 = sv[3];
        num[0]+=q*s0.x; num[1]+=q*s0.y; num[2]+=q*s0.z; num[3]+=q*s0.w;
        num[4]+=q*s1.x; num[5]+=q*s1.y; num[6]+=q*s1.z; num[7]+=q*s1.w;
        num[8]+=q*s2.x; num[9]+=q*s2.y; num[10]+=q*s2.z; num[11]+=q*s2.w;
        num[12]+=q*s3.x; num[13]+=q*s3.y; num[14]+=q*s3.z; num[15]+=q*s3.w;
    }
    for (int j = 0; j <= r; j++) {
        float aj = Amat[r][j];
        const float4* vv = (const float4*)&Vs[j][c0];
        float4 v0 = vv[0], v1 = vv[1], v2 = vv[2], v3 = vv[3];
        num[0]+=aj*v0.x; num[1]+=aj*v0.y; num[2]+=aj*v0.z; num[3]+=aj*v0.w;
        num[4]+=aj*v1.x; num[5]+=aj*v1.y; num[6]+=aj*v1.z; num[7]+=aj*v1.w;
        num[8]+=aj*v2.x; num[9]+=aj*v2.y; num[10]+=aj*v2.z; num[11]+=aj*v2.w;
        num[12]+=aj*v3.x; num[13]+=aj*v3.y; num[14]+=aj*v3.z; num[15]+=aj*v3.w;
    }
    float inv = 1.0f / den;
    float* op = attn + ((size_t)b * T_SEQ + ch*64 + r) * DM + h*64 + c0;
#pragma unroll
    for (int i = 0; i < 4; i++) {
        float4 ov = make_float4(num[i*4+0]*inv, num[i*4+1]*inv,
                                num[i*4+2]*inv, num[i*4+3]*inv);
        *(float4*)(op + i*4) = ov;
    }
}

extern "C" void kernel_launch(void* const* d_in, const int* in_sizes, int n_in,
                              void* d_out, int out_size, void* d_ws, size_t ws_size,
                              hipStream_t stream)
{
    (void)in_sizes; (void)n_in; (void)out_size; (void)ws_size;
    const float* x     = (const float*)d_in[0];
    const float* ln1_g = (const float*)d_in[1];
    const float* ln1_b = (const float*)d_in[2];
    const float* Wq = (const float*)d_in[3];
    const float* bq = (const float*)d_in[4];
    const float* Wk = (const float*)d_in[5];
    const float* bk = (const float*)d_in[6];
    const float* Wv = (const float*)d_in[7];
    const float* bv = (const float*)d_in[8];
    const float* Wo = (const float*)d_in[9];
    const float* bo = (const float*)d_in[10];
    const float* ln2_g = (const float*)d_in[11];
    const float* ln2_b = (const float*)d_in[12];
    const float* W1 = (const float*)d_in[13];
    const float* b1 = (const float*)d_in[14];
    const float* W2 = (const float*)d_in[15];
    const float* b2 = (const float*)d_in[16];
    float* out = (float*)d_out;
    float* ws  = (float*)d_ws;

    float* h    = ws;                  // 2,097,152 floats
    float* Qb   = ws + 2097152;
    float* Kb   = ws + 4194304;
    float* Vb   = ws + 6291456;
    float* St   = ws + 8388608;        // 16*32*4160 = 2,129,920
    float* X2   = ws + 10518528;
    float* FF   = ws + 12615680;       // 8,388,608 -> total 21,004,288 floats (~80 MB)
    float* attn = h;                   // reuse (h dead after QKV GEMMs)
    float* h2   = Qb;                  // reuse (Q dead after attn_out)

    ln_kernel<<<MROWS, 128, 0, stream>>>(x, ln1_g, ln1_b, h);

    dim3 g512(512/64, MROWS/128);
    gemm_k<1,true,false><<<g512, 256, 0, stream>>>(h, Wq, bq, nullptr, Qb, MROWS, 512, 512);
    gemm_k<1,true,false><<<g512, 256, 0, stream>>>(h, Wk, bk, nullptr, Kb, MROWS, 512, 512);
    gemm_k<0,true,false><<<g512, 256, 0, stream>>>(h, Wv, bv, nullptr, Vb, MROWS, 512, 512);

    attn_chunk_sum<<<BHN*NCHUNK, 256, 0, stream>>>(Kb, Vb, St);
    attn_scan<<<BHN, 256, 0, stream>>>(St);
    attn_out_k<<<BHN*NCHUNK, 256, 0, stream>>>(Qb, Kb, Vb, St, attn);

    gemm_k<0,false,true><<<g512, 256, 0, stream>>>(attn, Wo, bo, x, X2, MROWS, 512, 512);
    ln_kernel<<<MROWS, 128, 0, stream>>>(X2, ln2_g, ln2_b, h2);
    gemm_k<2,false,false><<<dim3(DFF/64, MROWS/128), 256, 0, stream>>>(h2, W1, b1, nullptr, FF, MROWS, DFF, 512);
    gemm_k<0,false,true><<<g512, 256, 0, stream>>>(FF, W2, b2, X2, out, MROWS, 512, DFF);
}

// Round 2
// 272.517 us; speedup vs baseline: 2.5247x; 2.5247x over previous
//
#include <hip/hip_runtime.h>
#include <hip/hip_bf16.h>
#include <cstdint>

#define T_SEQ   2048
#define DM      512
#define NH      8
#define DH      64
#define BATCH   2
#define MROWS   4096   // B*T
#define DFF     2048
#define CHUNK   64
#define NCHUNK  32
#define BHN     16
#define ST_STRIDE 4160 // 64*64 + 64

typedef __attribute__((ext_vector_type(8))) short bf16x8;
typedef __attribute__((ext_vector_type(4))) float f32x4;
typedef __hip_bfloat16 bf16;

__device__ __forceinline__ void g2lds16(const bf16* g, bf16* l) {
    __builtin_amdgcn_global_load_lds(
        (const __attribute__((address_space(1))) unsigned int*)g,
        (__attribute__((address_space(3))) unsigned int*)l, 16, 0, 0);
}

// ---------------- LayerNorm: one block per row (512 floats) -> bf16 out ----
__global__ __launch_bounds__(128) void ln_kernel(
    const float* __restrict__ x, const float* __restrict__ g,
    const float* __restrict__ b, bf16* __restrict__ y)
{
    int row = blockIdx.x;
    int t = threadIdx.x;
    const float4* xr = (const float4*)(x + (size_t)row * DM);
    float4 v = xr[t];
    float s  = v.x + v.y + v.z + v.w;
    float s2 = v.x*v.x + v.y*v.y + v.z*v.z + v.w*v.w;
#pragma unroll
    for (int off = 32; off > 0; off >>= 1) {
        s  += __shfl_down(s,  off);
        s2 += __shfl_down(s2, off);
    }
    __shared__ float sh[4];
    if ((t & 63) == 0) { sh[(t >> 6) * 2] = s; sh[(t >> 6) * 2 + 1] = s2; }
    __syncthreads();
    s  = sh[0] + sh[2];
    s2 = sh[1] + sh[3];
    float mu  = s * (1.0f / DM);
    float var = s2 * (1.0f / DM) - mu * mu;
    float rs  = rsqrtf(var + 1e-5f);
    float4 gg = ((const float4*)g)[t];
    float4 bb = ((const float4*)b)[t];
    union { short4 s4; bf16 h[4]; } u;
    u.h[0] = __float2bfloat16((v.x - mu) * rs * gg.x + bb.x);
    u.h[1] = __float2bfloat16((v.y - mu) * rs * gg.y + bb.y);
    u.h[2] = __float2bfloat16((v.z - mu) * rs * gg.z + bb.z);
    u.h[3] = __float2bfloat16((v.w - mu) * rs * gg.w + bb.w);
    *(short4*)(y + (size_t)row * DM + t * 4) = u.s4;
}

// ---------------- weight transpose+convert: src[K][N] f32 -> dst[N][K] bf16
__global__ __launch_bounds__(256) void wcvt_t(
    const float* __restrict__ src, bf16* __restrict__ dst, int K, int N)
{
    __shared__ float tile[64][65];
    int tid = threadIdx.x;
    int k0 = blockIdx.y * 64, n0 = blockIdx.x * 64;
    int tr = tid >> 4, tc = (tid & 15) * 4;
#pragma unroll
    for (int i = 0; i < 4; i++) {
        float4 v = *(const float4*)(src + (size_t)(k0 + tr + i*16) * N + n0 + tc);
        tile[tr + i*16][tc+0] = v.x; tile[tr + i*16][tc+1] = v.y;
        tile[tr + i*16][tc+2] = v.z; tile[tr + i*16][tc+3] = v.w;
    }
    __syncthreads();
#pragma unroll
    for (int i = 0; i < 4; i++) {
        int n = tr + i*16;
        union { short4 s4; bf16 h[4]; } u;
#pragma unroll
        for (int j = 0; j < 4; j++) u.h[j] = __float2bfloat16(tile[tc+j][n]);
        *(short4*)(dst + (size_t)(n0 + n) * K + k0 + tc) = u.s4;
    }
}

// ---------------- bf16 MFMA GEMM: C = A[M,K] @ Bt[N,K]^T ------------------
// MODE 0: QKV fused -> head-layout fp32 Q,K,V with elu+1 on Q,K
// MODE 1: fp32 outF = acc + bias0 + res
// MODE 2: bf16 outB = relu(acc + bias0)
template<int BM, int BN, int MODE>
__global__ __launch_bounds__(256) void mfma_gemm(
    const bf16* __restrict__ A, const bf16* __restrict__ Bt,
    const float* __restrict__ bias0, const float* __restrict__ bias1,
    const float* __restrict__ bias2, const float* __restrict__ res,
    float* __restrict__ outF,
    float* __restrict__ outQ, float* __restrict__ outK, float* __restrict__ outV,
    bf16* __restrict__ outB, int M, int N, int K)
{
    constexpr int BK = 64;
    constexpr int WTM = BM / 2, WTN = BN / 2;
    constexpr int FM = WTM / 16, FN = WTN / 16;
    __shared__ bf16 As[BM * BK];
    __shared__ bf16 Bs[BN * BK];
    const int tid = threadIdx.x;
    const int w = tid >> 6, lane = tid & 63;
    const int wr = w >> 1, wc = w & 1;
    const int bm0 = blockIdx.y * BM, bn0 = blockIdx.x * BN;
    const int srow = lane >> 3;            // 0..7 within chunk
    const int scol = (lane & 7) * 8;       // bf16 col element

    f32x4 acc[FM][FN];
#pragma unroll
    for (int m = 0; m < FM; m++)
#pragma unroll
        for (int n = 0; n < FN; n++) acc[m][n] = (f32x4){0.f,0.f,0.f,0.f};

    for (int k0 = 0; k0 < K; k0 += BK) {
#pragma unroll
        for (int i = 0; i < BM/32; i++) {
            int c = i*4 + w;
            g2lds16(A + (size_t)(bm0 + c*8 + srow) * K + k0 + scol, &As[c*512]);
        }
#pragma unroll
        for (int i = 0; i < BN/32; i++) {
            int c = i*4 + w;
            g2lds16(Bt + (size_t)(bn0 + c*8 + srow) * K + k0 + scol, &Bs[c*512]);
        }
        __syncthreads();
#pragma unroll
        for (int kk = 0; kk < 2; kk++) {
            bf16x8 af[FM], bfr[FN];
#pragma unroll
            for (int m = 0; m < FM; m++)
                af[m] = *(const bf16x8*)&As[(wr*WTM + m*16 + (lane&15))*BK + kk*32 + (lane>>4)*8];
#pragma unroll
            for (int n = 0; n < FN; n++)
                bfr[n] = *(const bf16x8*)&Bs[(wc*WTN + n*16 + (lane&15))*BK + kk*32 + (lane>>4)*8];
#pragma unroll
            for (int m = 0; m < FM; m++)
#pragma unroll
                for (int n = 0; n < FN; n++)
                    acc[m][n] = __builtin_amdgcn_mfma_f32_16x16x32_bf16(af[m], bfr[n], acc[m][n], 0, 0, 0);
        }
        __syncthreads();
    }

    const int lr = (lane >> 4) * 4;
    const int lc = lane & 15;
#pragma unroll
    for (int m = 0; m < FM; m++) {
#pragma unroll
        for (int n = 0; n < FN; n++) {
            int col = bn0 + wc*WTN + n*16 + lc;
#pragma unroll
            for (int j = 0; j < 4; j++) {
                int r = bm0 + wr*WTM + m*16 + lr + j;
                float v = acc[m][n][j];
                if (MODE == 0) {
                    int which = col >> 9;
                    int cc = col & 511;
                    float bv_ = which == 0 ? bias0[cc] : which == 1 ? bias1[cc] : bias2[cc];
                    v += bv_;
                    if (which < 2) v = v > 0.f ? v + 1.f : __expf(v);
                    int hh = cc >> 6, dd = cc & 63;
                    int bb = r >> 11, tt = r & 2047;
                    float* dst = which == 0 ? outQ : which == 1 ? outK : outV;
                    dst[((((size_t)(bb*NH + hh)) * T_SEQ + tt) << 6) + dd] = v;
                } else if (MODE == 1) {
                    v += bias0[col] + res[(size_t)r * N + col];
                    outF[(size_t)r * N + col] = v;
                } else {
                    v += bias0[col];
                    v = fmaxf(v, 0.f);
                    outB[(size_t)r * N + col] = __float2bfloat16(v);
                }
            }
        }
    }
}

// ---------------- attention phase 1: per-chunk K^T V and colsum(K) ---------
__global__ __launch_bounds__(256) void attn_chunk_sum(
    const float* __restrict__ Kb, const float* __restrict__ Vb,
    float* __restrict__ St)
{
    int blk = blockIdx.x;
    const float* Kp = Kb + (size_t)blk * (CHUNK * DH);
    const float* Vp = Vb + (size_t)blk * (CHUNK * DH);
    float* Sp = St + (size_t)blk * ST_STRIDE;
    __shared__ float Ks[64][64];
    __shared__ float Vs[64][64];
    int tid = threadIdx.x;
#pragma unroll
    for (int i = 0; i < 4; i++) {
        ((float4*)Ks)[tid + i*256] = ((const float4*)Kp)[tid + i*256];
        ((float4*)Vs)[tid + i*256] = ((const float4*)Vp)[tid + i*256];
    }
    __syncthreads();
    int r  = tid >> 2;
    int c0 = (tid & 3) * 16;
    float s[16];
#pragma unroll
    for (int i = 0; i < 16; i++) s[i] = 0.0f;
    for (int t = 0; t < 64; t++) {
        float kv = Ks[t][r];
        const float4* vr = (const float4*)&Vs[t][c0];
        float4 v0 = vr[0], v1 = vr[1], v2 = vr[2], v3 = vr[3];
        s[0]+=kv*v0.x; s[1]+=kv*v0.y; s[2]+=kv*v0.z; s[3]+=kv*v0.w;
        s[4]+=kv*v1.x; s[5]+=kv*v1.y; s[6]+=kv*v1.z; s[7]+=kv*v1.w;
        s[8]+=kv*v2.x; s[9]+=kv*v2.y; s[10]+=kv*v2.z; s[11]+=kv*v2.w;
        s[12]+=kv*v3.x; s[13]+=kv*v3.y; s[14]+=kv*v3.z; s[15]+=kv*v3.w;
    }
#pragma unroll
    for (int i = 0; i < 4; i++) {
        float4 ov = make_float4(s[i*4+0], s[i*4+1], s[i*4+2], s[i*4+3]);
        *(float4*)(Sp + (size_t)r*64 + c0 + i*4) = ov;
    }
    if (tid < 64) {
        float z = 0.0f;
        for (int t = 0; t < 64; t++) z += Ks[t][tid];
        Sp[4096 + tid] = z;
    }
}

// ---------------- attention phase 2: exclusive prefix over chunks ----------
__global__ __launch_bounds__(256) void attn_scan(float* __restrict__ St)
{
    int bh = blockIdx.x;
    float* Sp = St + (size_t)bh * NCHUNK * ST_STRIDE;
    int tid = threadIdx.x;
    float4 run[4];
#pragma unroll
    for (int i = 0; i < 4; i++) run[i] = make_float4(0,0,0,0);
    float rz = 0.0f;
    for (int ch = 0; ch < NCHUNK; ch++) {
        float4* p4 = (float4*)(Sp + (size_t)ch * ST_STRIDE);
#pragma unroll
        for (int i = 0; i < 4; i++) {
            float4 t = p4[tid*4 + i];
            p4[tid*4 + i] = run[i];
            run[i].x += t.x; run[i].y += t.y; run[i].z += t.z; run[i].w += t.w;
        }
        if (tid < 64) {
            float* zp = Sp + (size_t)ch * ST_STRIDE + 4096;
            float t = zp[tid];
            zp[tid] = rz;
            rz += t;
        }
    }
}

// ---------------- attention phase 3: per-chunk output -> bf16 --------------
__global__ __launch_bounds__(256) void attn_out_k(
    const float* __restrict__ Qb, const float* __restrict__ Kb,
    const float* __restrict__ Vb, const float* __restrict__ St,
    bf16* __restrict__ attnb)
{
    int blk = blockIdx.x;
    int bh = blk >> 5, ch = blk & 31;
    int b = bh >> 3, h = bh & 7;
    const float* Qp = Qb + (size_t)blk * 4096;
    const float* Kp = Kb + (size_t)blk * 4096;
    const float* Vp = Vb + (size_t)blk * 4096;
    const float* Sp = St + (size_t)blk * ST_STRIDE;
    __shared__ float Qs[64][68];
    __shared__ float Kt[64][68];
    __shared__ float Vs[64][68];
    __shared__ float Ss[64][68];
    __shared__ float Amat[64][65];
    __shared__ float zs[64];
    int tid = threadIdx.x;
#pragma unroll
    for (int i = 0; i < 4; i++) {
        int fi = tid + i*256;
        int t  = fi >> 4;
        int d4 = (fi & 15) * 4;
        float4 q = ((const float4*)Qp)[fi];
        float4 k = ((const float4*)Kp)[fi];
        float4 v = ((const float4*)Vp)[fi];
        float4 s = ((const float4*)Sp)[fi];
        *(float4*)&Qs[t][d4] = q;
        *(float4*)&Vs[t][d4] = v;
        *(float4*)&Ss[t][d4] = s;
        Kt[d4+0][t] = k.x; Kt[d4+1][t] = k.y; Kt[d4+2][t] = k.z; Kt[d4+3][t] = k.w;
    }
    if (tid < 64) zs[tid] = Sp[4096 + tid];
    __syncthreads();
    int r  = tid >> 2;
    int c0 = (tid & 3) * 16;
    float a[16];
#pragma unroll
    for (int i = 0; i < 16; i++) a[i] = 0.0f;
    for (int d = 0; d < 64; d++) {
        float q = Qs[r][d];
        const float4* kr = (const float4*)&Kt[d][c0];
        float4 k0 = kr[0], k1 = kr[1], k2 = kr[2], k3 = kr[3];
        a[0]+=q*k0.x; a[1]+=q*k0.y; a[2]+=q*k0.z; a[3]+=q*k0.w;
        a[4]+=q*k1.x; a[5]+=q*k1.y; a[6]+=q*k1.z; a[7]+=q*k1.w;
        a[8]+=q*k2.x; a[9]+=q*k2.y; a[10]+=q*k2.z; a[11]+=q*k2.w;
        a[12]+=q*k3.x; a[13]+=q*k3.y; a[14]+=q*k3.z; a[15]+=q*k3.w;
    }
#pragma unroll
    for (int i = 0; i < 16; i++) Amat[r][c0+i] = a[i];
    __syncthreads();
    float den = 0.0f;
    for (int d = 0; d < 64; d++) den += Qs[r][d] * zs[d];
    for (int j = 0; j <= r; j++) den += Amat[r][j];
    den = fmaxf(den, 1e-6f);
    float num[16];
#pragma unroll
    for (int i = 0; i < 16; i++) num[i] = 0.0f;
    for (int d = 0; d < 64; d++) {
        float q = Qs[r][d];
        const float4* sv = (const float4*)&Ss[d][c0];
        float4 s0 = sv[0], s1 = sv[1], s2 = sv[2], s3 = sv[3];
        num[0]+=q*s0.x; num[1]+=q*s0.y; num[2]+=q*s0.z; num[3]+=q*s0.w;
        num[4]+=q*s1.x; num[5]+=q*s1.y; num[6]+=q*s1.z; num[7]+=q*s1.w;
        num[8]+=q*s2.x; num[9]+=q*s2.y; num[10]+=q*s2.z; num[11]+=q*s2.w;
        num[12]+=q*s3.x; num[13]+=q*s3.y; num[14]+=q*s3.z; num[15]+=q*s3.w;
    }
    for (int j = 0; j <= r; j++) {
        float aj = Amat[r][j];
        const float4* vv = (const float4*)&Vs[j][c0];
        float4 v0 = vv[0], v1 = vv[1], v2 = vv[2], v3 = vv[3];
        num[0]+=aj*v0.x; num[1]+=aj*v0.y; num[2]+=aj*v0.z; num[3]+=aj*v0.w;
        num[4]+=aj*v1.x; num[5]+=aj*v1.y; num[6]+=aj*v1.z; num[7]+=aj*v1.w;
        num[8]+=aj*v2.x; num[9]+=aj*v2.y; num[10]+=aj*v2.z; num[11]+=aj*v2.w;
        num[12]+=aj*v3.x; num[13]+=aj*v3.y; num[14]+=aj*v3.z; num[15]+=aj*v3.w;
    }
    float inv = 1.0f / den;
    union { short4 s4[4]; bf16 hh[16]; } u;
#pragma unroll
    for (int i = 0; i < 16; i++) u.hh[i] = __float2bfloat16(num[i] * inv);
    short4* op = (short4*)(attnb + ((size_t)b * T_SEQ + ch*64 + r) * DM + h*64 + c0);
#pragma unroll
    for (int i = 0; i < 4; i++) op[i] = u.s4[i];
}

extern "C" void kernel_launch(void* const* d_in, const int* in_sizes, int n_in,
                              void* d_out, int out_size, void* d_ws, size_t ws_size,
                              hipStream_t stream)
{
    (void)in_sizes; (void)n_in; (void)out_size; (void)ws_size;
    const float* x     = (const float*)d_in[0];
    const float* ln1_g = (const float*)d_in[1];
    const float* ln1_b = (const float*)d_in[2];
    const float* Wq = (const float*)d_in[3];
    const float* bq = (const float*)d_in[4];
    const float* Wk = (const float*)d_in[5];
    const float* bk = (const float*)d_in[6];
    const float* Wv = (const float*)d_in[7];
    const float* bv = (const float*)d_in[8];
    const float* Wo = (const float*)d_in[9];
    const float* bo = (const float*)d_in[10];
    const float* ln2_g = (const float*)d_in[11];
    const float* ln2_b = (const float*)d_in[12];
    const float* W1 = (const float*)d_in[13];
    const float* b1 = (const float*)d_in[14];
    const float* W2 = (const float*)d_in[15];
    const float* b2 = (const float*)d_in[16];
    float* out = (float*)d_out;
    char* base = (char*)d_ws;

    bf16*  h_bf  = (bf16*)(base + 0);
    bf16*  h2_bf = (bf16*)(base + 4194304);
    bf16*  attnb = (bf16*)(base + 8388608);
    bf16*  QKVWT = (bf16*)(base + 12582912);
    bf16*  WoT   = (bf16*)(base + 14155776);
    bf16*  W1T   = (bf16*)(base + 14680064);
    bf16*  W2T   = (bf16*)(base + 16777216);
    float* Qb    = (float*)(base + 18874368);
    float* Kb    = (float*)(base + 27262976);
    float* Vb    = (float*)(base + 35651584);
    float* St    = (float*)(base + 44040192);
    float* X2    = (float*)(base + 52559872);
    bf16*  FF    = (bf16*)(base + 60948480);

    // weight convert+transpose (bf16, [N][K])
    wcvt_t<<<dim3(8, 8),  256, 0, stream>>>(Wq, QKVWT,            512, 512);
    wcvt_t<<<dim3(8, 8),  256, 0, stream>>>(Wk, QKVWT + 512*512,  512, 512);
    wcvt_t<<<dim3(8, 8),  256, 0, stream>>>(Wv, QKVWT + 1024*512, 512, 512);
    wcvt_t<<<dim3(8, 8),  256, 0, stream>>>(Wo, WoT, 512, 512);
    wcvt_t<<<dim3(32, 8), 256, 0, stream>>>(W1, W1T, 512, DFF);
    wcvt_t<<<dim3(8, 32), 256, 0, stream>>>(W2, W2T, DFF, 512);

    ln_kernel<<<MROWS, 128, 0, stream>>>(x, ln1_g, ln1_b, h_bf);

    // fused QKV: [4096,512] @ [512,1536] -> head-layout fp32 Q,K,V
    mfma_gemm<128,128,0><<<dim3(12, 32), 256, 0, stream>>>(
        h_bf, QKVWT, bq, bk, bv, nullptr, nullptr, Qb, Kb, Vb, nullptr,
        MROWS, 1536, 512);

    attn_chunk_sum<<<BHN*NCHUNK, 256, 0, stream>>>(Kb, Vb, St);
    attn_scan<<<BHN, 256, 0, stream>>>(St);
    attn_out_k<<<BHN*NCHUNK, 256, 0, stream>>>(Qb, Kb, Vb, St, attnb);

    // X2 = attn @ Wo + bo + x
    mfma_gemm<64,128,1><<<dim3(4, 64), 256, 0, stream>>>(
        attnb, WoT, bo, nullptr, nullptr, x, X2, nullptr, nullptr, nullptr, nullptr,
        MROWS, 512, 512);

    ln_kernel<<<MROWS, 128, 0, stream>>>(X2, ln2_g, ln2_b, h2_bf);

    // FF = relu(h2 @ W1 + b1)  (bf16)
    mfma_gemm<128,128,2><<<dim3(16, 32), 256, 0, stream>>>(
        h2_bf, W1T, b1, nullptr, nullptr, nullptr, nullptr, nullptr, nullptr, nullptr, FF,
        MROWS, DFF, 512);

    // out = FF @ W2 + b2 + X2
    mfma_gemm<64,128,1><<<dim3(4, 64), 256, 0, stream>>>(
        FF, W2T, b2, nullptr, nullptr, X2, out, nullptr, nullptr, nullptr, nullptr,
        MROWS, 512, DFF);
}

// Round 3
// 233.044 us; speedup vs baseline: 2.9523x; 1.1694x over previous
//
#include <hip/hip_runtime.h>
#include <hip/hip_bf16.h>
#include <cstdint>

#define T_SEQ   2048
#define DM      512
#define NH      8
#define DH      64
#define BATCH   2
#define MROWS   4096   // B*T
#define DFF     2048
#define CHUNK   64
#define NCHUNK  32
#define BHN     16
#define ST_STRIDE 4160 // 64*64 + 64

typedef __attribute__((ext_vector_type(8))) short bf16x8;
typedef __attribute__((ext_vector_type(4))) float f32x4;
typedef __hip_bfloat16 bf16;

__device__ __forceinline__ void g2lds16(const bf16* g, bf16* l) {
    __builtin_amdgcn_global_load_lds(
        (const __attribute__((address_space(1))) unsigned int*)g,
        (__attribute__((address_space(3))) unsigned int*)l, 16, 0, 0);
}

// ---------------- LayerNorm: one block per row (512 floats) -> bf16 out ----
__global__ __launch_bounds__(128) void ln_kernel(
    const float* __restrict__ x, const float* __restrict__ g,
    const float* __restrict__ b, bf16* __restrict__ y)
{
    int row = blockIdx.x;
    int t = threadIdx.x;
    const float4* xr = (const float4*)(x + (size_t)row * DM);
    float4 v = xr[t];
    float s  = v.x + v.y + v.z + v.w;
    float s2 = v.x*v.x + v.y*v.y + v.z*v.z + v.w*v.w;
#pragma unroll
    for (int off = 32; off > 0; off >>= 1) {
        s  += __shfl_down(s,  off);
        s2 += __shfl_down(s2, off);
    }
    __shared__ float sh[4];
    if ((t & 63) == 0) { sh[(t >> 6) * 2] = s; sh[(t >> 6) * 2 + 1] = s2; }
    __syncthreads();
    s  = sh[0] + sh[2];
    s2 = sh[1] + sh[3];
    float mu  = s * (1.0f / DM);
    float var = s2 * (1.0f / DM) - mu * mu;
    float rs  = rsqrtf(var + 1e-5f);
    float4 gg = ((const float4*)g)[t];
    float4 bb = ((const float4*)b)[t];
    union { short4 s4; bf16 h[4]; } u;
    u.h[0] = __float2bfloat16((v.x - mu) * rs * gg.x + bb.x);
    u.h[1] = __float2bfloat16((v.y - mu) * rs * gg.y + bb.y);
    u.h[2] = __float2bfloat16((v.z - mu) * rs * gg.z + bb.z);
    u.h[3] = __float2bfloat16((v.w - mu) * rs * gg.w + bb.w);
    *(short4*)(y + (size_t)row * DM + t * 4) = u.s4;
}

// ------------- fused weight transpose+convert: 6 matrices in 1 dispatch ----
// blocks 0..255: Wq/Wk/Wv/Wo (64 tiles each); 256..511: W1; 512..767: W2
__global__ __launch_bounds__(256) void wcvt_all(
    const float* __restrict__ Wq, const float* __restrict__ Wk,
    const float* __restrict__ Wv, const float* __restrict__ Wo,
    const float* __restrict__ W1, const float* __restrict__ W2,
    bf16* __restrict__ QKVWT, bf16* __restrict__ WoT,
    bf16* __restrict__ W1T, bf16* __restrict__ W2T)
{
    __shared__ float tile[64][65];
    int bid = blockIdx.x;
    const float* src; bf16* dst; int K, N, txi, tyi;
    if (bid < 256) {
        int m = bid >> 6, t = bid & 63;
        src = m == 0 ? Wq : m == 1 ? Wk : m == 2 ? Wv : Wo;
        dst = m == 0 ? QKVWT : m == 1 ? QKVWT + 512*512
            : m == 2 ? QKVWT + 1024*512 : WoT;
        K = 512; N = 512; txi = t & 7; tyi = t >> 3;
    } else if (bid < 512) {
        int t = bid - 256;
        src = W1; dst = W1T; K = 512; N = 2048; txi = t & 31; tyi = t >> 5;
    } else {
        int t = bid - 512;
        src = W2; dst = W2T; K = 2048; N = 512; txi = t & 7; tyi = t >> 3;
    }
    int k0 = tyi * 64, n0 = txi * 64;
    int tid = threadIdx.x;
    int tr = tid >> 4, tc = (tid & 15) * 4;
#pragma unroll
    for (int i = 0; i < 4; i++) {
        float4 v = *(const float4*)(src + (size_t)(k0 + tr + i*16) * N + n0 + tc);
        tile[tr + i*16][tc+0] = v.x; tile[tr + i*16][tc+1] = v.y;
        tile[tr + i*16][tc+2] = v.z; tile[tr + i*16][tc+3] = v.w;
    }
    __syncthreads();
#pragma unroll
    for (int i = 0; i < 4; i++) {
        int n = tr + i*16;
        union { short4 s4; bf16 h[4]; } u;
#pragma unroll
        for (int j = 0; j < 4; j++) u.h[j] = __float2bfloat16(tile[tc+j][n]);
        *(short4*)(dst + (size_t)(n0 + n) * K + k0 + tc) = u.s4;
    }
}

// ---------------- bf16 MFMA GEMM: C = A[M,K] @ Bt[N,K]^T ------------------
// MODE 0: QKV fused -> head-layout fp32 Q,K,V with elu+1 on Q,K
// MODE 1: fp32 outF = acc + bias0 + res
// MODE 2: bf16 outB = relu(acc + bias0)
template<int BM, int BN, int MODE>
__global__ __launch_bounds__(256) void mfma_gemm(
    const bf16* __restrict__ A, const bf16* __restrict__ Bt,
    const float* __restrict__ bias0, const float* __restrict__ bias1,
    const float* __restrict__ bias2, const float* __restrict__ res,
    float* __restrict__ outF,
    float* __restrict__ outQ, float* __restrict__ outK, float* __restrict__ outV,
    bf16* __restrict__ outB, int M, int N, int K)
{
    constexpr int BK = 64;
    constexpr int WTM = BM / 2, WTN = BN / 2;
    constexpr int FM = WTM / 16, FN = WTN / 16;
    __shared__ bf16 As[BM * BK];
    __shared__ bf16 Bs[BN * BK];
    const int tid = threadIdx.x;
    const int w = tid >> 6, lane = tid & 63;
    const int wr = w >> 1, wc = w & 1;
    const int bm0 = blockIdx.y * BM, bn0 = blockIdx.x * BN;
    const int srow = lane >> 3;
    const int scol = (lane & 7) * 8;

    f32x4 acc[FM][FN];
#pragma unroll
    for (int m = 0; m < FM; m++)
#pragma unroll
        for (int n = 0; n < FN; n++) acc[m][n] = (f32x4){0.f,0.f,0.f,0.f};

    for (int k0 = 0; k0 < K; k0 += BK) {
#pragma unroll
        for (int i = 0; i < BM/32; i++) {
            int c = i*4 + w;
            g2lds16(A + (size_t)(bm0 + c*8 + srow) * K + k0 + scol, &As[c*512]);
        }
#pragma unroll
        for (int i = 0; i < BN/32; i++) {
            int c = i*4 + w;
            g2lds16(Bt + (size_t)(bn0 + c*8 + srow) * K + k0 + scol, &Bs[c*512]);
        }
        __syncthreads();
#pragma unroll
        for (int kk = 0; kk < 2; kk++) {
            bf16x8 af[FM], bfr[FN];
#pragma unroll
            for (int m = 0; m < FM; m++)
                af[m] = *(const bf16x8*)&As[(wr*WTM + m*16 + (lane&15))*BK + kk*32 + (lane>>4)*8];
#pragma unroll
            for (int n = 0; n < FN; n++)
                bfr[n] = *(const bf16x8*)&Bs[(wc*WTN + n*16 + (lane&15))*BK + kk*32 + (lane>>4)*8];
#pragma unroll
            for (int m = 0; m < FM; m++)
#pragma unroll
                for (int n = 0; n < FN; n++)
                    acc[m][n] = __builtin_amdgcn_mfma_f32_16x16x32_bf16(af[m], bfr[n], acc[m][n], 0, 0, 0);
        }
        __syncthreads();
    }

    const int lr = (lane >> 4) * 4;
    const int lc = lane & 15;
#pragma unroll
    for (int m = 0; m < FM; m++) {
#pragma unroll
        for (int n = 0; n < FN; n++) {
            int col = bn0 + wc*WTN + n*16 + lc;
#pragma unroll
            for (int j = 0; j < 4; j++) {
                int r = bm0 + wr*WTM + m*16 + lr + j;
                float v = acc[m][n][j];
                if (MODE == 0) {
                    int which = col >> 9;
                    int cc = col & 511;
                    float bv_ = which == 0 ? bias0[cc] : which == 1 ? bias1[cc] : bias2[cc];
                    v += bv_;
                    if (which < 2) v = v > 0.f ? v + 1.f : __expf(v);
                    int hh = cc >> 6, dd = cc & 63;
                    int bb = r >> 11, tt = r & 2047;
                    float* dst = which == 0 ? outQ : which == 1 ? outK : outV;
                    dst[((((size_t)(bb*NH + hh)) * T_SEQ + tt) << 6) + dd] = v;
                } else if (MODE == 1) {
                    v += bias0[col] + res[(size_t)r * N + col];
                    outF[(size_t)r * N + col] = v;
                } else {
                    v += bias0[col];
                    v = fmaxf(v, 0.f);
                    outB[(size_t)r * N + col] = __float2bfloat16(v);
                }
            }
        }
    }
}

// ---------------- attention phase 1: per-chunk K^T V and colsum(K) ---------
__global__ __launch_bounds__(256) void attn_chunk_sum(
    const float* __restrict__ Kb, const float* __restrict__ Vb,
    float* __restrict__ St)
{
    int blk = blockIdx.x;
    const float* Kp = Kb + (size_t)blk * (CHUNK * DH);
    const float* Vp = Vb + (size_t)blk * (CHUNK * DH);
    float* Sp = St + (size_t)blk * ST_STRIDE;
    __shared__ float Ks[64][64];
    __shared__ float Vs[64][64];
    int tid = threadIdx.x;
#pragma unroll
    for (int i = 0; i < 4; i++) {
        ((float4*)Ks)[tid + i*256] = ((const float4*)Kp)[tid + i*256];
        ((float4*)Vs)[tid + i*256] = ((const float4*)Vp)[tid + i*256];
    }
    __syncthreads();
    int r  = tid >> 2;
    int c0 = (tid & 3) * 16;
    float s[16];
#pragma unroll
    for (int i = 0; i < 16; i++) s[i] = 0.0f;
    for (int t = 0; t < 64; t++) {
        float kv = Ks[t][r];
        const float4* vr = (const float4*)&Vs[t][c0];
        float4 v0 = vr[0], v1 = vr[1], v2 = vr[2], v3 = vr[3];
        s[0]+=kv*v0.x; s[1]+=kv*v0.y; s[2]+=kv*v0.z; s[3]+=kv*v0.w;
        s[4]+=kv*v1.x; s[5]+=kv*v1.y; s[6]+=kv*v1.z; s[7]+=kv*v1.w;
        s[8]+=kv*v2.x; s[9]+=kv*v2.y; s[10]+=kv*v2.z; s[11]+=kv*v2.w;
        s[12]+=kv*v3.x; s[13]+=kv*v3.y; s[14]+=kv*v3.z; s[15]+=kv*v3.w;
    }
#pragma unroll
    for (int i = 0; i < 4; i++) {
        float4 ov = make_float4(s[i*4+0], s[i*4+1], s[i*4+2], s[i*4+3]);
        *(float4*)(Sp + (size_t)r*64 + c0 + i*4) = ov;
    }
    if (tid < 64) {
        float z = 0.0f;
        for (int t = 0; t < 64; t++) z += Ks[t][tid];
        Sp[4096 + tid] = z;
    }
}

// -------- attention phase 2: exclusive prefix over chunks (parallel) -------
// one thread per (bh, float4-elem): 16 * 1040 columns, scan length 32
__global__ __launch_bounds__(64) void attn_scan(float* __restrict__ St)
{
    int f4 = blockIdx.x * 64 + threadIdx.x;     // 0..1087
    if (f4 >= ST_STRIDE / 4) return;            // 1040 float4 per chunk
    int bh = blockIdx.y;
    float4* base = (float4*)(St + (size_t)bh * NCHUNK * ST_STRIDE) + f4;
    float4 run = make_float4(0.f, 0.f, 0.f, 0.f);
#pragma unroll 4
    for (int ch = 0; ch < NCHUNK; ch++) {
        float4* p = base + (size_t)ch * (ST_STRIDE / 4);
        float4 t = *p;
        *p = run;
        run.x += t.x; run.y += t.y; run.z += t.z; run.w += t.w;
    }
}

// ---------------- attention phase 3: per-chunk output -> bf16 --------------
__global__ __launch_bounds__(256) void attn_out_k(
    const float* __restrict__ Qb, const float* __restrict__ Kb,
    const float* __restrict__ Vb, const float* __restrict__ St,
    bf16* __restrict__ attnb)
{
    int blk = blockIdx.x;
    int bh = blk >> 5, ch = blk & 31;
    int b = bh >> 3, h = bh & 7;
    const float* Qp = Qb + (size_t)blk * 4096;
    const float* Kp = Kb + (size_t)blk * 4096;
    const float* Vp = Vb + (size_t)blk * 4096;
    const float* Sp = St + (size_t)blk * ST_STRIDE;
    __shared__ float Qs[64][68];
    __shared__ float Kt[64][68];
    __shared__ float Vs[64][68];
    __shared__ float Ss[64][68];
    __shared__ float Amat[64][65];
    __shared__ float zs[64];
    int tid = threadIdx.x;
#pragma unroll
    for (int i = 0; i < 4; i++) {
        int fi = tid + i*256;
        int t  = fi >> 4;
        int d4 = (fi & 15) * 4;
        float4 q = ((const float4*)Qp)[fi];
        float4 k = ((const float4*)Kp)[fi];
        float4 v = ((const float4*)Vp)[fi];
        float4 s = ((const float4*)Sp)[fi];
        *(float4*)&Qs[t][d4] = q;
        *(float4*)&Vs[t][d4] = v;
        *(float4*)&Ss[t][d4] = s;
        Kt[d4+0][t] = k.x; Kt[d4+1][t] = k.y; Kt[d4+2][t] = k.z; Kt[d4+3][t] = k.w;
    }
    if (tid < 64) zs[tid] = Sp[4096 + tid];
    __syncthreads();
    int r  = tid >> 2;
    int c0 = (tid & 3) * 16;
    float a[16];
#pragma unroll
    for (int i = 0; i < 16; i++) a[i] = 0.0f;
    for (int d = 0; d < 64; d++) {
        float q = Qs[r][d];
        const float4* kr = (const float4*)&Kt[d][c0];
        float4 k0 = kr[0], k1 = kr[1], k2 = kr[2], k3 = kr[3];
        a[0]+=q*k0.x; a[1]+=q*k0.y; a[2]+=q*k0.z; a[3]+=q*k0.w;
        a[4]+=q*k1.x; a[5]+=q*k1.y; a[6]+=q*k1.z; a[7]+=q*k1.w;
        a[8]+=q*k2.x; a[9]+=q*k2.y; a[10]+=q*k2.z; a[11]+=q*k2.w;
        a[12]+=q*k3.x; a[13]+=q*k3.y; a[14]+=q*k3.z; a[15]+=q*k3.w;
    }
#pragma unroll
    for (int i = 0; i < 16; i++) Amat[r][c0+i] = a[i];
    __syncthreads();
    float den = 0.0f;
    for (int d = 0; d < 64; d++) den += Qs[r][d] * zs[d];
    for (int j = 0; j <= r; j++) den += Amat[r][j];
    den = fmaxf(den, 1e-6f);
    float num[16];
#pragma unroll
    for (int i = 0; i < 16; i++) num[i] = 0.0f;
    for (int d = 0; d < 64; d++) {
        float q = Qs[r][d];
        const float4* sv = (const float4*)&Ss[d][c0];
        float4 s0 = sv[0], s1 = sv[1], s2 = sv[2], s3 = sv[3];
        num[0]+=q*s0.x; num[1]+=q*s0.y; num[2]+=q*s0.z; num[3]+=q*s0.w;
        num[4]+=q*s1.x; num[5]+=q*s1.y; num[6]+=q*s1.z; num[7]+=q*s1.w;
        num[8]+=q*s2.x; num[9]+=q*s2.y; num[10]+=q*s2.z; num[11]+=q*s2.w;
        num[12]+=q*s3.x; num[13]+=q*s3.y; num[14]+=q*s3.z; num[15]+=q*s3.w;
    }
    for (int j = 0; j <= r; j++) {
        float aj = Amat[r][j];
        const float4* vv = (const float4*)&Vs[j][c0];
        float4 v0 = vv[0], v1 = vv[1], v2 = vv[2], v3 = vv[3];
        num[0]+=aj*v0.x; num[1]+=aj*v0.y; num[2]+=aj*v0.z; num[3]+=aj*v0.w;
        num[4]+=aj*v1.x; num[5]+=aj*v1.y; num[6]+=aj*v1.z; num[7]+=aj*v1.w;
        num[8]+=aj*v2.x; num[9]+=aj*v2.y; num[10]+=aj*v2.z; num[11]+=aj*v2.w;
        num[12]+=aj*v3.x; num[13]+=aj*v3.y; num[14]+=aj*v3.z; num[15]+=aj*v3.w;
    }
    float inv = 1.0f / den;
    union { short4 s4[4]; bf16 hh[16]; } u;
#pragma unroll
    for (int i = 0; i < 16; i++) u.hh[i] = __float2bfloat16(num[i] * inv);
    short4* op = (short4*)(attnb + ((size_t)b * T_SEQ + ch*64 + r) * DM + h*64 + c0);
#pragma unroll
    for (int i = 0; i < 4; i++) op[i] = u.s4[i];
}

extern "C" void kernel_launch(void* const* d_in, const int* in_sizes, int n_in,
                              void* d_out, int out_size, void* d_ws, size_t ws_size,
                              hipStream_t stream)
{
    (void)in_sizes; (void)n_in; (void)out_size; (void)ws_size;
    const float* x     = (const float*)d_in[0];
    const float* ln1_g = (const float*)d_in[1];
    const float* ln1_b = (const float*)d_in[2];
    const float* Wq = (const float*)d_in[3];
    const float* bq = (const float*)d_in[4];
    const float* Wk = (const float*)d_in[5];
    const float* bk = (const float*)d_in[6];
    const float* Wv = (const float*)d_in[7];
    const float* bv = (const float*)d_in[8];
    const float* Wo = (const float*)d_in[9];
    const float* bo = (const float*)d_in[10];
    const float* ln2_g = (const float*)d_in[11];
    const float* ln2_b = (const float*)d_in[12];
    const float* W1 = (const float*)d_in[13];
    const float* b1 = (const float*)d_in[14];
    const float* W2 = (const float*)d_in[15];
    const float* b2 = (const float*)d_in[16];
    float* out = (float*)d_out;
    char* base = (char*)d_ws;

    bf16*  h_bf  = (bf16*)(base + 0);
    bf16*  h2_bf = (bf16*)(base + 4194304);
    bf16*  attnb = (bf16*)(base + 8388608);
    bf16*  QKVWT = (bf16*)(base + 12582912);
    bf16*  WoT   = (bf16*)(base + 14155776);
    bf16*  W1T   = (bf16*)(base + 14680064);
    bf16*  W2T   = (bf16*)(base + 16777216);
    float* Qb    = (float*)(base + 18874368);
    float* Kb    = (float*)(base + 27262976);
    float* Vb    = (float*)(base + 35651584);
    float* St    = (float*)(base + 44040192);
    float* X2    = (float*)(base + 52559872);
    bf16*  FF    = (bf16*)(base + 60948480);

    wcvt_all<<<768, 256, 0, stream>>>(Wq, Wk, Wv, Wo, W1, W2,
                                      QKVWT, WoT, W1T, W2T);

    ln_kernel<<<MROWS, 128, 0, stream>>>(x, ln1_g, ln1_b, h_bf);

    // fused QKV: [4096,512] @ [512,1536] -> head-layout fp32 Q,K,V
    mfma_gemm<128,128,0><<<dim3(12, 32), 256, 0, stream>>>(
        h_bf, QKVWT, bq, bk, bv, nullptr, nullptr, Qb, Kb, Vb, nullptr,
        MROWS, 1536, 512);

    attn_chunk_sum<<<BHN*NCHUNK, 256, 0, stream>>>(Kb, Vb, St);
    attn_scan<<<dim3(17, BHN), 64, 0, stream>>>(St);
    attn_out_k<<<BHN*NCHUNK, 256, 0, stream>>>(Qb, Kb, Vb, St, attnb);

    // X2 = attn @ Wo + bo + x
    mfma_gemm<64,128,1><<<dim3(4, 64), 256, 0, stream>>>(
        attnb, WoT, bo, nullptr, nullptr, x, X2, nullptr, nullptr, nullptr, nullptr,
        MROWS, 512, 512);

    ln_kernel<<<MROWS, 128, 0, stream>>>(X2, ln2_g, ln2_b, h2_bf);

    // FF = relu(h2 @ W1 + b1)  (bf16)
    mfma_gemm<128,128,2><<<dim3(16, 32), 256, 0, stream>>>(
        h2_bf, W1T, b1, nullptr, nullptr, nullptr, nullptr, nullptr, nullptr, nullptr, FF,
        MROWS, DFF, 512);

    // out = FF @ W2 + b2 + X2
    mfma_gemm<64,128,1><<<dim3(4, 64), 256, 0, stream>>>(
        FF, W2T, b2, nullptr, nullptr, X2, out, nullptr, nullptr, nullptr, nullptr,
        MROWS, 512, DFF);
}

// Round 4
// 228.722 us; speedup vs baseline: 3.0081x; 1.0189x over previous
//
#include <hip/hip_runtime.h>
#include <hip/hip_bf16.h>
#include <cstdint>

#define T_SEQ   2048
#define DM      512
#define NH      8
#define DH      64
#define BATCH   2
#define MROWS   4096   // B*T
#define DFF     2048
#define CHUNK   64
#define NCHUNK  32
#define BHN     16
#define ST_STRIDE 4160 // 64*64 + 64

typedef __attribute__((ext_vector_type(8))) short bf16x8;
typedef __attribute__((ext_vector_type(4))) float f32x4;
typedef __hip_bfloat16 bf16;

__device__ __forceinline__ void g2lds16(const bf16* g, bf16* l) {
    __builtin_amdgcn_global_load_lds(
        (const __attribute__((address_space(1))) unsigned int*)g,
        (__attribute__((address_space(3))) unsigned int*)l, 16, 0, 0);
}

// ---------------- LayerNorm: one block per row (512 floats) -> bf16 out ----
// INIT: also write oinit = x_row + b2 (pre-init for split-K atomic GEMM)
template<bool INIT>
__global__ __launch_bounds__(128) void ln_kernel(
    const float* __restrict__ x, const float* __restrict__ g,
    const float* __restrict__ b, bf16* __restrict__ y,
    const float* __restrict__ b2, float* __restrict__ oinit)
{
    int row = blockIdx.x;
    int t = threadIdx.x;
    const float4* xr = (const float4*)(x + (size_t)row * DM);
    float4 v = xr[t];
    float s  = v.x + v.y + v.z + v.w;
    float s2 = v.x*v.x + v.y*v.y + v.z*v.z + v.w*v.w;
#pragma unroll
    for (int off = 32; off > 0; off >>= 1) {
        s  += __shfl_down(s,  off);
        s2 += __shfl_down(s2, off);
    }
    __shared__ float sh[4];
    if ((t & 63) == 0) { sh[(t >> 6) * 2] = s; sh[(t >> 6) * 2 + 1] = s2; }
    __syncthreads();
    s  = sh[0] + sh[2];
    s2 = sh[1] + sh[3];
    float mu  = s * (1.0f / DM);
    float var = s2 * (1.0f / DM) - mu * mu;
    float rs  = rsqrtf(var + 1e-5f);
    float4 gg = ((const float4*)g)[t];
    float4 bb = ((const float4*)b)[t];
    union { short4 s4; bf16 h[4]; } u;
    u.h[0] = __float2bfloat16((v.x - mu) * rs * gg.x + bb.x);
    u.h[1] = __float2bfloat16((v.y - mu) * rs * gg.y + bb.y);
    u.h[2] = __float2bfloat16((v.z - mu) * rs * gg.z + bb.z);
    u.h[3] = __float2bfloat16((v.w - mu) * rs * gg.w + bb.w);
    *(short4*)(y + (size_t)row * DM + t * 4) = u.s4;
    if (INIT) {
        float4 b2v = ((const float4*)b2)[t];
        float4 ov = make_float4(v.x + b2v.x, v.y + b2v.y, v.z + b2v.z, v.w + b2v.w);
        ((float4*)(oinit + (size_t)row * DM))[t] = ov;
    }
}

// ------------- fused weight transpose+convert: 6 matrices in 1 dispatch ----
__global__ __launch_bounds__(256) void wcvt_all(
    const float* __restrict__ Wq, const float* __restrict__ Wk,
    const float* __restrict__ Wv, const float* __restrict__ Wo,
    const float* __restrict__ W1, const float* __restrict__ W2,
    bf16* __restrict__ QKVWT, bf16* __restrict__ WoT,
    bf16* __restrict__ W1T, bf16* __restrict__ W2T)
{
    __shared__ float tile[64][65];
    int bid = blockIdx.x;
    const float* src; bf16* dst; int K, N, txi, tyi;
    if (bid < 256) {
        int m = bid >> 6, t = bid & 63;
        src = m == 0 ? Wq : m == 1 ? Wk : m == 2 ? Wv : Wo;
        dst = m == 0 ? QKVWT : m == 1 ? QKVWT + 512*512
            : m == 2 ? QKVWT + 1024*512 : WoT;
        K = 512; N = 512; txi = t & 7; tyi = t >> 3;
    } else if (bid < 512) {
        int t = bid - 256;
        src = W1; dst = W1T; K = 512; N = 2048; txi = t & 31; tyi = t >> 5;
    } else {
        int t = bid - 512;
        src = W2; dst = W2T; K = 2048; N = 512; txi = t & 7; tyi = t >> 3;
    }
    int k0 = tyi * 64, n0 = txi * 64;
    int tid = threadIdx.x;
    int tr = tid >> 4, tc = (tid & 15) * 4;
#pragma unroll
    for (int i = 0; i < 4; i++) {
        float4 v = *(const float4*)(src + (size_t)(k0 + tr + i*16) * N + n0 + tc);
        tile[tr + i*16][tc+0] = v.x; tile[tr + i*16][tc+1] = v.y;
        tile[tr + i*16][tc+2] = v.z; tile[tr + i*16][tc+3] = v.w;
    }
    __syncthreads();
#pragma unroll
    for (int i = 0; i < 4; i++) {
        int n = tr + i*16;
        union { short4 s4; bf16 h[4]; } u;
#pragma unroll
        for (int j = 0; j < 4; j++) u.h[j] = __float2bfloat16(tile[tc+j][n]);
        *(short4*)(dst + (size_t)(n0 + n) * K + k0 + tc) = u.s4;
    }
}

// ---------------- bf16 MFMA GEMM: C = A[M,K] @ Bt[N,K]^T ------------------
// Waves arranged WM x WN. MODE 0: QKV fused -> head-layout fp32 Q,K,V (elu+1
// on Q,K). MODE 1: fp32 outF = acc + bias0 + res. MODE 2: bf16 outB =
// relu(acc+bias0). MODE 3: split-K over blockIdx.z, atomicAdd into outF.
template<int BM, int BN, int WM, int WN, int MODE>
__global__ __launch_bounds__(WM*WN*64) void mfma_gemm(
    const bf16* __restrict__ A, const bf16* __restrict__ Bt,
    const float* __restrict__ bias0, const float* __restrict__ bias1,
    const float* __restrict__ bias2, const float* __restrict__ res,
    float* __restrict__ outF,
    float* __restrict__ outQ, float* __restrict__ outK, float* __restrict__ outV,
    bf16* __restrict__ outB, int M, int N, int K)
{
    constexpr int BK = 64;
    constexpr int WAVES = WM * WN;
    constexpr int WTM = BM / WM, WTN = BN / WN;
    constexpr int FM = WTM / 16, FN = WTN / 16;
    constexpr int IA = BM / 8 / WAVES, IB = BN / 8 / WAVES;
    __shared__ bf16 As[BM * BK];
    __shared__ bf16 Bs[BN * BK];
    const int tid = threadIdx.x;
    const int w = tid >> 6, lane = tid & 63;
    const int wr = w / WN, wc = w % WN;
    const int bm0 = blockIdx.y * BM, bn0 = blockIdx.x * BN;
    const int srow = lane >> 3;
    const int scol = (lane & 7) * 8;

    int kbeg = 0, kend = K;
    if (MODE == 3) { int half = K >> 1; kbeg = blockIdx.z * half; kend = kbeg + half; }

    f32x4 acc[FM][FN];
#pragma unroll
    for (int m = 0; m < FM; m++)
#pragma unroll
        for (int n = 0; n < FN; n++) acc[m][n] = (f32x4){0.f,0.f,0.f,0.f};

    for (int k0 = kbeg; k0 < kend; k0 += BK) {
#pragma unroll
        for (int i = 0; i < IA; i++) {
            int c = i*WAVES + w;
            g2lds16(A + (size_t)(bm0 + c*8 + srow) * K + k0 + scol, &As[c*512]);
        }
#pragma unroll
        for (int i = 0; i < IB; i++) {
            int c = i*WAVES + w;
            g2lds16(Bt + (size_t)(bn0 + c*8 + srow) * K + k0 + scol, &Bs[c*512]);
        }
        __syncthreads();
#pragma unroll
        for (int kk = 0; kk < 2; kk++) {
            bf16x8 af[FM], bfr[FN];
#pragma unroll
            for (int m = 0; m < FM; m++)
                af[m] = *(const bf16x8*)&As[(wr*WTM + m*16 + (lane&15))*BK + kk*32 + (lane>>4)*8];
#pragma unroll
            for (int n = 0; n < FN; n++)
                bfr[n] = *(const bf16x8*)&Bs[(wc*WTN + n*16 + (lane&15))*BK + kk*32 + (lane>>4)*8];
#pragma unroll
            for (int m = 0; m < FM; m++)
#pragma unroll
                for (int n = 0; n < FN; n++)
                    acc[m][n] = __builtin_amdgcn_mfma_f32_16x16x32_bf16(af[m], bfr[n], acc[m][n], 0, 0, 0);
        }
        __syncthreads();
    }

    const int lr = (lane >> 4) * 4;
    const int lc = lane & 15;
#pragma unroll
    for (int m = 0; m < FM; m++) {
#pragma unroll
        for (int n = 0; n < FN; n++) {
            int col = bn0 + wc*WTN + n*16 + lc;
#pragma unroll
            for (int j = 0; j < 4; j++) {
                int r = bm0 + wr*WTM + m*16 + lr + j;
                float v = acc[m][n][j];
                if (MODE == 0) {
                    int which = col >> 9;
                    int cc = col & 511;
                    float bv_ = which == 0 ? bias0[cc] : which == 1 ? bias1[cc] : bias2[cc];
                    v += bv_;
                    if (which < 2) v = v > 0.f ? v + 1.f : __expf(v);
                    int hh = cc >> 6, dd = cc & 63;
                    int bb = r >> 11, tt = r & 2047;
                    float* dst = which == 0 ? outQ : which == 1 ? outK : outV;
                    dst[((((size_t)(bb*NH + hh)) * T_SEQ + tt) << 6) + dd] = v;
                } else if (MODE == 1) {
                    v += bias0[col] + res[(size_t)r * N + col];
                    outF[(size_t)r * N + col] = v;
                } else if (MODE == 2) {
                    v += bias0[col];
                    v = fmaxf(v, 0.f);
                    outB[(size_t)r * N + col] = __float2bfloat16(v);
                } else {
                    unsafeAtomicAdd(&outF[(size_t)r * N + col], v);
                }
            }
        }
    }
}

// ---------------- attention phase 1: per-chunk K^T V and colsum(K) ---------
__global__ __launch_bounds__(256) void attn_chunk_sum(
    const float* __restrict__ Kb, const float* __restrict__ Vb,
    float* __restrict__ St)
{
    int blk = blockIdx.x;
    const float* Kp = Kb + (size_t)blk * (CHUNK * DH);
    const float* Vp = Vb + (size_t)blk * (CHUNK * DH);
    float* Sp = St + (size_t)blk * ST_STRIDE;
    __shared__ float Ks[64][64];
    __shared__ float Vs[64][64];
    int tid = threadIdx.x;
#pragma unroll
    for (int i = 0; i < 4; i++) {
        ((float4*)Ks)[tid + i*256] = ((const float4*)Kp)[tid + i*256];
        ((float4*)Vs)[tid + i*256] = ((const float4*)Vp)[tid + i*256];
    }
    __syncthreads();
    int r  = tid >> 2;
    int c0 = (tid & 3) * 16;
    float s[16];
#pragma unroll
    for (int i = 0; i < 16; i++) s[i] = 0.0f;
    for (int t = 0; t < 64; t++) {
        float kv = Ks[t][r];
        const float4* vr = (const float4*)&Vs[t][c0];
        float4 v0 = vr[0], v1 = vr[1], v2 = vr[2], v3 = vr[3];
        s[0]+=kv*v0.x; s[1]+=kv*v0.y; s[2]+=kv*v0.z; s[3]+=kv*v0.w;
        s[4]+=kv*v1.x; s[5]+=kv*v1.y; s[6]+=kv*v1.z; s[7]+=kv*v1.w;
        s[8]+=kv*v2.x; s[9]+=kv*v2.y; s[10]+=kv*v2.z; s[11]+=kv*v2.w;
        s[12]+=kv*v3.x; s[13]+=kv*v3.y; s[14]+=kv*v3.z; s[15]+=kv*v3.w;
    }
#pragma unroll
    for (int i = 0; i < 4; i++) {
        float4 ov = make_float4(s[i*4+0], s[i*4+1], s[i*4+2], s[i*4+3]);
        *(float4*)(Sp + (size_t)r*64 + c0 + i*4) = ov;
    }
    if (tid < 64) {
        float z = 0.0f;
        for (int t = 0; t < 64; t++) z += Ks[t][tid];
        Sp[4096 + tid] = z;
    }
}

// -------- attention phase 2: exclusive prefix over chunks (parallel) -------
__global__ __launch_bounds__(64) void attn_scan(float* __restrict__ St)
{
    int f4 = blockIdx.x * 64 + threadIdx.x;
    if (f4 >= ST_STRIDE / 4) return;
    int bh = blockIdx.y;
    float4* base = (float4*)(St + (size_t)bh * NCHUNK * ST_STRIDE) + f4;
    float4 run = make_float4(0.f, 0.f, 0.f, 0.f);
#pragma unroll 4
    for (int ch = 0; ch < NCHUNK; ch++) {
        float4* p = base + (size_t)ch * (ST_STRIDE / 4);
        float4 t = *p;
        *p = run;
        run.x += t.x; run.y += t.y; run.z += t.z; run.w += t.w;
    }
}

// ---------------- attention phase 3: per-chunk output -> bf16 --------------
__global__ __launch_bounds__(256) void attn_out_k(
    const float* __restrict__ Qb, const float* __restrict__ Kb,
    const float* __restrict__ Vb, const float* __restrict__ St,
    bf16* __restrict__ attnb)
{
    int blk = blockIdx.x;
    int bh = blk >> 5, ch = blk & 31;
    int b = bh >> 3, h = bh & 7;
    const float* Qp = Qb + (size_t)blk * 4096;
    const float* Kp = Kb + (size_t)blk * 4096;
    const float* Vp = Vb + (size_t)blk * 4096;
    const float* Sp = St + (size_t)blk * ST_STRIDE;
    __shared__ float Qs[64][68];
    __shared__ float Kt[64][68];
    __shared__ float Vs[64][68];
    __shared__ float Ss[64][68];
    __shared__ float Amat[64][65];
    __shared__ float zs[64];
    int tid = threadIdx.x;
#pragma unroll
    for (int i = 0; i < 4; i++) {
        int fi = tid + i*256;
        int t  = fi >> 4;
        int d4 = (fi & 15) * 4;
        float4 q = ((const float4*)Qp)[fi];
        float4 k = ((const float4*)Kp)[fi];
        float4 v = ((const float4*)Vp)[fi];
        float4 s = ((const float4*)Sp)[fi];
        *(float4*)&Qs[t][d4] = q;
        *(float4*)&Vs[t][d4] = v;
        *(float4*)&Ss[t][d4] = s;
        Kt[d4+0][t] = k.x; Kt[d4+1][t] = k.y; Kt[d4+2][t] = k.z; Kt[d4+3][t] = k.w;
    }
    if (tid < 64) zs[tid] = Sp[4096 + tid];
    __syncthreads();
    int r  = tid >> 2;
    int c0 = (tid & 3) * 16;
    float a[16];
#pragma unroll
    for (int i = 0; i < 16; i++) a[i] = 0.0f;
    for (int d = 0; d < 64; d++) {
        float q = Qs[r][d];
        const float4* kr = (const float4*)&Kt[d][c0];
        float4 k0 = kr[0], k1 = kr[1], k2 = kr[2], k3 = kr[3];
        a[0]+=q*k0.x; a[1]+=q*k0.y; a[2]+=q*k0.z; a[3]+=q*k0.w;
        a[4]+=q*k1.x; a[5]+=q*k1.y; a[6]+=q*k1.z; a[7]+=q*k1.w;
        a[8]+=q*k2.x; a[9]+=q*k2.y; a[10]+=q*k2.z; a[11]+=q*k2.w;
        a[12]+=q*k3.x; a[13]+=q*k3.y; a[14]+=q*k3.z; a[15]+=q*k3.w;
    }
#pragma unroll
    for (int i = 0; i < 16; i++) Amat[r][c0+i] = a[i];
    __syncthreads();
    float den = 0.0f;
    for (int d = 0; d < 64; d++) den += Qs[r][d] * zs[d];
    for (int j = 0; j <= r; j++) den += Amat[r][j];
    den = fmaxf(den, 1e-6f);
    float num[16];
#pragma unroll
    for (int i = 0; i < 16; i++) num[i] = 0.0f;
    for (int d = 0; d < 64; d++) {
        float q = Qs[r][d];
        const float4* sv = (const float4*)&Ss[d][c0];
        float4 s0 = sv[0], s1 = sv[1], s2 = sv[2], s3 = sv[3];
        num[0]+=q*s0.x; num[1]+=q*s0.y; num[2]+=q*s0.z; num[3]+=q*s0.w;
        num[4]+=q*s1.x; num[5]+=q*s1.y; num[6]+=q*s1.z; num[7]+=q*s1.w;
        num[8]+=q*s2.x; num[9]+=q*s2.y; num[10]+=q*s2.z; num[11]+=q*s2.w;
        num[12]+=q*s3.x; num[13]+=q*s3.y; num[14]+=q*s3.z; num[15]+=q*s3.w;
    }
    for (int j = 0; j <= r; j++) {
        float aj = Amat[r][j];
        const float4* vv = (const float4*)&Vs[j][c0];
        float4 v0 = vv[0], v1 = vv[1], v2 = vv[2], v3 = vv[3];
        num[0]+=aj*v0.x; num[1]+=aj*v0.y; num[2]+=aj*v0.z; num[3]+=aj*v0.w;
        num[4]+=aj*v1.x; num[5]+=aj*v1.y; num[6]+=aj*v1.z; num[7]+=aj*v1.w;
        num[8]+=aj*v2.x; num[9]+=aj*v2.y; num[10]+=aj*v2.z; num[11]+=aj*v2.w;
        num[12]+=aj*v3.x; num[13]+=aj*v3.y; num[14]+=aj*v3.z; num[15]+=aj*v3.w;
    }
    float inv = 1.0f / den;
    union { short4 s4[4]; bf16 hh[16]; } u;
#pragma unroll
    for (int i = 0; i < 16; i++) u.hh[i] = __float2bfloat16(num[i] * inv);
    short4* op = (short4*)(attnb + ((size_t)b * T_SEQ + ch*64 + r) * DM + h*64 + c0);
#pragma unroll
    for (int i = 0; i < 4; i++) op[i] = u.s4[i];
}

extern "C" void kernel_launch(void* const* d_in, const int* in_sizes, int n_in,
                              void* d_out, int out_size, void* d_ws, size_t ws_size,
                              hipStream_t stream)
{
    (void)in_sizes; (void)n_in; (void)out_size; (void)ws_size;
    const float* x     = (const float*)d_in[0];
    const float* ln1_g = (const float*)d_in[1];
    const float* ln1_b = (const float*)d_in[2];
    const float* Wq = (const float*)d_in[3];
    const float* bq = (const float*)d_in[4];
    const float* Wk = (const float*)d_in[5];
    const float* bk = (const float*)d_in[6];
    const float* Wv = (const float*)d_in[7];
    const float* bv = (const float*)d_in[8];
    const float* Wo = (const float*)d_in[9];
    const float* bo = (const float*)d_in[10];
    const float* ln2_g = (const float*)d_in[11];
    const float* ln2_b = (const float*)d_in[12];
    const float* W1 = (const float*)d_in[13];
    const float* b1 = (const float*)d_in[14];
    const float* W2 = (const float*)d_in[15];
    const float* b2 = (const float*)d_in[16];
    float* out = (float*)d_out;
    char* base = (char*)d_ws;

    bf16*  h_bf  = (bf16*)(base + 0);
    bf16*  h2_bf = (bf16*)(base + 4194304);
    bf16*  attnb = (bf16*)(base + 8388608);
    bf16*  QKVWT = (bf16*)(base + 12582912);
    bf16*  WoT   = (bf16*)(base + 14155776);
    bf16*  W1T   = (bf16*)(base + 14680064);
    bf16*  W2T   = (bf16*)(base + 16777216);
    float* Qb    = (float*)(base + 18874368);
    float* Kb    = (float*)(base + 27262976);
    float* Vb    = (float*)(base + 35651584);
    float* St    = (float*)(base + 44040192);
    float* X2    = (float*)(base + 52559872);
    bf16*  FF    = (bf16*)(base + 60948480);

    wcvt_all<<<768, 256, 0, stream>>>(Wq, Wk, Wv, Wo, W1, W2,
                                      QKVWT, WoT, W1T, W2T);

    ln_kernel<false><<<MROWS, 128, 0, stream>>>(x, ln1_g, ln1_b, h_bf, nullptr, nullptr);

    // fused QKV: [4096,512] @ [512,1536], 8-wave blocks
    mfma_gemm<128,128,4,2,0><<<dim3(12, 32), 512, 0, stream>>>(
        h_bf, QKVWT, bq, bk, bv, nullptr, nullptr, Qb, Kb, Vb, nullptr,
        MROWS, 1536, 512);

    attn_chunk_sum<<<BHN*NCHUNK, 256, 0, stream>>>(Kb, Vb, St);
    attn_scan<<<dim3(17, BHN), 64, 0, stream>>>(St);
    attn_out_k<<<BHN*NCHUNK, 256, 0, stream>>>(Qb, Kb, Vb, St, attnb);

    // X2 = attn @ Wo + bo + x   (64x64 tiles -> 512 blocks)
    mfma_gemm<64,64,2,2,1><<<dim3(8, 64), 256, 0, stream>>>(
        attnb, WoT, bo, nullptr, nullptr, x, X2, nullptr, nullptr, nullptr, nullptr,
        MROWS, 512, 512);

    // ln2 + pre-init out = X2 + b2
    ln_kernel<true><<<MROWS, 128, 0, stream>>>(X2, ln2_g, ln2_b, h2_bf, b2, out);

    // FF = relu(h2 @ W1 + b1)  (bf16), 8-wave blocks
    mfma_gemm<128,128,4,2,2><<<dim3(16, 32), 512, 0, stream>>>(
        h2_bf, W1T, b1, nullptr, nullptr, nullptr, nullptr, nullptr, nullptr, nullptr, FF,
        MROWS, DFF, 512);

    // out += FF @ W2 (split-K=2, atomic fp32 add)
    mfma_gemm<128,64,2,2,3><<<dim3(8, 32, 2), 256, 0, stream>>>(
        FF, W2T, nullptr, nullptr, nullptr, nullptr, out, nullptr, nullptr, nullptr, nullptr,
        MROWS, 512, 2048);
}

// Round 6
// 212.593 us; speedup vs baseline: 3.2363x; 1.0759x over previous
//
#include <hip/hip_runtime.h>
#include <hip/hip_bf16.h>
#include <cstdint>

#define T_SEQ   2048
#define DM      512
#define NH      8
#define DH      64
#define BATCH   2
#define MROWS   4096   // B*T
#define DFF     2048
#define CHUNK   64
#define NCHUNK  32
#define BHN     16
#define ST_STRIDE 4160 // 64*64 + 64

typedef __attribute__((ext_vector_type(8))) short bf16x8;
typedef __attribute__((ext_vector_type(4))) float f32x4;
typedef __hip_bfloat16 bf16;

__device__ __forceinline__ void g2lds16(const bf16* g, bf16* l) {
    __builtin_amdgcn_global_load_lds(
        (const __attribute__((address_space(1))) unsigned int*)g,
        (__attribute__((address_space(3))) unsigned int*)l, 16, 0, 0);
}

__device__ __forceinline__ float b2f(short s) {
    union { unsigned u; float f; } x;
    x.u = ((unsigned)(unsigned short)s) << 16;
    return x.f;
}

// bijective XCD-chunked block swizzle (m204): consecutive linear ids -> same XCD
__device__ __forceinline__ void xcd_swizzle(int gx, int gy, int& bx, int& by) {
    int lin = by * gx + bx;
    int nwg = gx * gy;
    int q = nwg >> 3, r = nwg & 7;
    int xcd = lin & 7, loc = lin >> 3;
    int swz = (xcd < r ? xcd * (q + 1) : r * (q + 1) + (xcd - r) * q) + loc;
    bx = swz % gx; by = swz / gx;
}

// ---------------- LayerNorm: one block per row (512 floats) -> bf16 out ----
// INIT: also write oinit = x_row + b2 (pre-init for split-K atomic GEMM)
template<bool INIT>
__global__ __launch_bounds__(128) void ln_kernel(
    const float* __restrict__ x, const float* __restrict__ g,
    const float* __restrict__ b, bf16* __restrict__ y,
    const float* __restrict__ b2, float* __restrict__ oinit)
{
    int row = blockIdx.x;
    int t = threadIdx.x;
    const float4* xr = (const float4*)(x + (size_t)row * DM);
    float4 v = xr[t];
    float s  = v.x + v.y + v.z + v.w;
    float s2 = v.x*v.x + v.y*v.y + v.z*v.z + v.w*v.w;
#pragma unroll
    for (int off = 32; off > 0; off >>= 1) {
        s  += __shfl_down(s,  off);
        s2 += __shfl_down(s2, off);
    }
    __shared__ float sh[4];
    if ((t & 63) == 0) { sh[(t >> 6) * 2] = s; sh[(t >> 6) * 2 + 1] = s2; }
    __syncthreads();
    s  = sh[0] + sh[2];
    s2 = sh[1] + sh[3];
    float mu  = s * (1.0f / DM);
    float var = s2 * (1.0f / DM) - mu * mu;
    float rs  = rsqrtf(var + 1e-5f);
    float4 gg = ((const float4*)g)[t];
    float4 bb = ((const float4*)b)[t];
    union { short4 s4; bf16 h[4]; } u;
    u.h[0] = __float2bfloat16((v.x - mu) * rs * gg.x + bb.x);
    u.h[1] = __float2bfloat16((v.y - mu) * rs * gg.y + bb.y);
    u.h[2] = __float2bfloat16((v.z - mu) * rs * gg.z + bb.z);
    u.h[3] = __float2bfloat16((v.w - mu) * rs * gg.w + bb.w);
    *(short4*)(y + (size_t)row * DM + t * 4) = u.s4;
    if (INIT) {
        float4 b2v = ((const float4*)b2)[t];
        float4 ov = make_float4(v.x + b2v.x, v.y + b2v.y, v.z + b2v.z, v.w + b2v.w);
        ((float4*)(oinit + (size_t)row * DM))[t] = ov;
    }
}

// ------------- fused weight transpose+convert: 6 matrices in 1 dispatch ----
__global__ __launch_bounds__(256) void wcvt_all(
    const float* __restrict__ Wq, const float* __restrict__ Wk,
    const float* __restrict__ Wv, const float* __restrict__ Wo,
    const float* __restrict__ W1, const float* __restrict__ W2,
    bf16* __restrict__ QKVWT, bf16* __restrict__ WoT,
    bf16* __restrict__ W1T, bf16* __restrict__ W2T)
{
    __shared__ float tile[64][65];
    int bid = blockIdx.x;
    const float* src; bf16* dst; int K, N, txi, tyi;
    if (bid < 256) {
        int m = bid >> 6, t = bid & 63;
        src = m == 0 ? Wq : m == 1 ? Wk : m == 2 ? Wv : Wo;
        dst = m == 0 ? QKVWT : m == 1 ? QKVWT + 512*512
            : m == 2 ? QKVWT + 1024*512 : WoT;
        K = 512; N = 512; txi = t & 7; tyi = t >> 3;
    } else if (bid < 512) {
        int t = bid - 256;
        src = W1; dst = W1T; K = 512; N = 2048; txi = t & 31; tyi = t >> 5;
    } else {
        int t = bid - 512;
        src = W2; dst = W2T; K = 2048; N = 512; txi = t & 7; tyi = t >> 3;
    }
    int k0 = tyi * 64, n0 = txi * 64;
    int tid = threadIdx.x;
    int tr = tid >> 4, tc = (tid & 15) * 4;
#pragma unroll
    for (int i = 0; i < 4; i++) {
        float4 v = *(const float4*)(src + (size_t)(k0 + tr + i*16) * N + n0 + tc);
        tile[tr + i*16][tc+0] = v.x; tile[tr + i*16][tc+1] = v.y;
        tile[tr + i*16][tc+2] = v.z; tile[tr + i*16][tc+3] = v.w;
    }
    __syncthreads();
#pragma unroll
    for (int i = 0; i < 4; i++) {
        int n = tr + i*16;
        union { short4 s4; bf16 h[4]; } u;
#pragma unroll
        for (int j = 0; j < 4; j++) u.h[j] = __float2bfloat16(tile[tc+j][n]);
        *(short4*)(dst + (size_t)(n0 + n) * K + k0 + tc) = u.s4;
    }
}

// ---------------- bf16 MFMA GEMM: C = A[M,K] @ Bt[N,K]^T ------------------
// MODE 0: QKV fused -> head-layout bf16 Q,K,V (elu+1 on Q,K)
// MODE 1: fp32 outF = acc + bias0 + res
// MODE 2: bf16 outB = relu(acc+bias0)
// MODE 3: split-K over blockIdx.z, atomicAdd into outF
template<int BM, int BN, int WM, int WN, int MODE>
__global__ __launch_bounds__(WM*WN*64) void mfma_gemm(
    const bf16* __restrict__ A, const bf16* __restrict__ Bt,
    const float* __restrict__ bias0, const float* __restrict__ bias1,
    const float* __restrict__ bias2, const float* __restrict__ res,
    float* __restrict__ outF,
    bf16* __restrict__ outQ, bf16* __restrict__ outK, bf16* __restrict__ outV,
    bf16* __restrict__ outB, int M, int N, int K)
{
    constexpr int BK = 64;
    constexpr int WAVES = WM * WN;
    constexpr int WTM = BM / WM, WTN = BN / WN;
    constexpr int FM = WTM / 16, FN = WTN / 16;
    constexpr int IA = BM / 8 / WAVES, IB = BN / 8 / WAVES;
    __shared__ bf16 As[BM * BK];
    __shared__ bf16 Bs[BN * BK];
    const int tid = threadIdx.x;
    const int w = tid >> 6, lane = tid & 63;
    const int wr = w / WN, wc = w % WN;
    int bx = blockIdx.x, by = blockIdx.y;
    xcd_swizzle(gridDim.x, gridDim.y, bx, by);
    const int bm0 = by * BM, bn0 = bx * BN;
    const int srow = lane >> 3;
    const int scol = (lane & 7) * 8;

    int kbeg = 0, kend = K;
    if (MODE == 3) { int half = K >> 1; kbeg = blockIdx.z * half; kend = kbeg + half; }

    f32x4 acc[FM][FN];
#pragma unroll
    for (int m = 0; m < FM; m++)
#pragma unroll
        for (int n = 0; n < FN; n++) acc[m][n] = (f32x4){0.f,0.f,0.f,0.f};

    for (int k0 = kbeg; k0 < kend; k0 += BK) {
#pragma unroll
        for (int i = 0; i < IA; i++) {
            int c = i*WAVES + w;
            g2lds16(A + (size_t)(bm0 + c*8 + srow) * K + k0 + scol, &As[c*512]);
        }
#pragma unroll
        for (int i = 0; i < IB; i++) {
            int c = i*WAVES + w;
            g2lds16(Bt + (size_t)(bn0 + c*8 + srow) * K + k0 + scol, &Bs[c*512]);
        }
        __syncthreads();
#pragma unroll
        for (int kk = 0; kk < 2; kk++) {
            bf16x8 af[FM], bfr[FN];
#pragma unroll
            for (int m = 0; m < FM; m++)
                af[m] = *(const bf16x8*)&As[(wr*WTM + m*16 + (lane&15))*BK + kk*32 + (lane>>4)*8];
#pragma unroll
            for (int n = 0; n < FN; n++)
                bfr[n] = *(const bf16x8*)&Bs[(wc*WTN + n*16 + (lane&15))*BK + kk*32 + (lane>>4)*8];
#pragma unroll
            for (int m = 0; m < FM; m++)
#pragma unroll
                for (int n = 0; n < FN; n++)
                    acc[m][n] = __builtin_amdgcn_mfma_f32_16x16x32_bf16(af[m], bfr[n], acc[m][n], 0, 0, 0);
        }
        __syncthreads();
    }

    const int lr = (lane >> 4) * 4;
    const int lc = lane & 15;
#pragma unroll
    for (int m = 0; m < FM; m++) {
#pragma unroll
        for (int n = 0; n < FN; n++) {
            int col = bn0 + wc*WTN + n*16 + lc;
#pragma unroll
            for (int j = 0; j < 4; j++) {
                int r = bm0 + wr*WTM + m*16 + lr + j;
                float v = acc[m][n][j];
                if (MODE == 0) {
                    int which = col >> 9;
                    int cc = col & 511;
                    float bv_ = which == 0 ? bias0[cc] : which == 1 ? bias1[cc] : bias2[cc];
                    v += bv_;
                    if (which < 2) v = v > 0.f ? v + 1.f : __expf(v);
                    int hh = cc >> 6, dd = cc & 63;
                    int bb = r >> 11, tt = r & 2047;
                    bf16* dst = which == 0 ? outQ : which == 1 ? outK : outV;
                    dst[((((size_t)(bb*NH + hh)) * T_SEQ + tt) << 6) + dd] = __float2bfloat16(v);
                } else if (MODE == 1) {
                    v += bias0[col] + res[(size_t)r * N + col];
                    outF[(size_t)r * N + col] = v;
                } else if (MODE == 2) {
                    v += bias0[col];
                    v = fmaxf(v, 0.f);
                    outB[(size_t)r * N + col] = __float2bfloat16(v);
                } else {
                    unsafeAtomicAdd(&outF[(size_t)r * N + col], v);
                }
            }
        }
    }
}

// ---------------- attention phase 1: per-chunk K^T V and colsum(K) ---------
__global__ __launch_bounds__(256) void attn_chunk_sum(
    const bf16* __restrict__ Kb, const bf16* __restrict__ Vb,
    float* __restrict__ St)
{
    int blk = blockIdx.x;
    const bf16* Kp = Kb + (size_t)blk * (CHUNK * DH);
    const bf16* Vp = Vb + (size_t)blk * (CHUNK * DH);
    float* Sp = St + (size_t)blk * ST_STRIDE;
    __shared__ float Ks[64][64];
    __shared__ float Vs[64][64];
    int tid = threadIdx.x;
#pragma unroll
    for (int i = 0; i < 2; i++) {
        int idx = tid + i*256;             // bf16x8 index 0..511
        int t = idx >> 3, d8 = (idx & 7) * 8;
        bf16x8 k8 = ((const bf16x8*)Kp)[idx];
        bf16x8 v8 = ((const bf16x8*)Vp)[idx];
#pragma unroll
        for (int j = 0; j < 8; j++) {
            Ks[t][d8+j] = b2f(k8[j]);
            Vs[t][d8+j] = b2f(v8[j]);
        }
    }
    __syncthreads();
    int r  = tid >> 2;
    int c0 = (tid & 3) * 16;
    float s[16];
#pragma unroll
    for (int i = 0; i < 16; i++) s[i] = 0.0f;
    for (int t = 0; t < 64; t++) {
        float kv = Ks[t][r];
        const float4* vr = (const float4*)&Vs[t][c0];
        float4 v0 = vr[0], v1 = vr[1], v2 = vr[2], v3 = vr[3];
        s[0]+=kv*v0.x; s[1]+=kv*v0.y; s[2]+=kv*v0.z; s[3]+=kv*v0.w;
        s[4]+=kv*v1.x; s[5]+=kv*v1.y; s[6]+=kv*v1.z; s[7]+=kv*v1.w;
        s[8]+=kv*v2.x; s[9]+=kv*v2.y; s[10]+=kv*v2.z; s[11]+=kv*v2.w;
        s[12]+=kv*v3.x; s[13]+=kv*v3.y; s[14]+=kv*v3.z; s[15]+=kv*v3.w;
    }
#pragma unroll
    for (int i = 0; i < 4; i++) {
        float4 ov = make_float4(s[i*4+0], s[i*4+1], s[i*4+2], s[i*4+3]);
        *(float4*)(Sp + (size_t)r*64 + c0 + i*4) = ov;
    }
    if (tid < 64) {
        float z = 0.0f;
        for (int t = 0; t < 64; t++) z += Ks[t][tid];
        Sp[4096 + tid] = z;
    }
}

// -------- attention phase 2: exclusive prefix over chunks (parallel) -------
__global__ __launch_bounds__(64) void attn_scan(float* __restrict__ St)
{
    int f4 = blockIdx.x * 64 + threadIdx.x;
    if (f4 >= ST_STRIDE / 4) return;
    int bh = blockIdx.y;
    float4* base = (float4*)(St + (size_t)bh * NCHUNK * ST_STRIDE) + f4;
    float4 run = make_float4(0.f, 0.f, 0.f, 0.f);
#pragma unroll 4
    for (int ch = 0; ch < NCHUNK; ch++) {
        float4* p = base + (size_t)ch * (ST_STRIDE / 4);
        float4 t = *p;
        *p = run;
        run.x += t.x; run.y += t.y; run.z += t.z; run.w += t.w;
    }
}

// ---------------- attention phase 3: per-chunk output -> bf16 --------------
__global__ __launch_bounds__(256) void attn_out_k(
    const bf16* __restrict__ Qb, const bf16* __restrict__ Kb,
    const bf16* __restrict__ Vb, const float* __restrict__ St,
    bf16* __restrict__ attnb)
{
    int blk = blockIdx.x;
    int bh = blk >> 5, ch = blk & 31;
    int b = bh >> 3, h = bh & 7;
    const bf16*  Qp = Qb + (size_t)blk * 4096;
    const bf16*  Kp = Kb + (size_t)blk * 4096;
    const bf16*  Vp = Vb + (size_t)blk * 4096;
    const float* Sp = St + (size_t)blk * ST_STRIDE;
    __shared__ float Qs[64][68];
    __shared__ float Kt[64][68];
    __shared__ float Vs[64][68];
    __shared__ float Ss[64][68];
    __shared__ bf16  Amat[64][72];
    __shared__ float zs[64];
    int tid = threadIdx.x;
#pragma unroll
    for (int i = 0; i < 2; i++) {
        int idx = tid + i*256;             // bf16x8 index 0..511
        int t = idx >> 3, d8 = (idx & 7) * 8;
        bf16x8 q8 = ((const bf16x8*)Qp)[idx];
        bf16x8 k8 = ((const bf16x8*)Kp)[idx];
        bf16x8 v8 = ((const bf16x8*)Vp)[idx];
#pragma unroll
        for (int j = 0; j < 8; j++) {
            Qs[t][d8+j] = b2f(q8[j]);
            Vs[t][d8+j] = b2f(v8[j]);
            Kt[d8+j][t] = b2f(k8[j]);
        }
    }
#pragma unroll
    for (int i = 0; i < 4; i++) {
        int fi = tid + i*256;              // float4 index 0..1023
        int t  = fi >> 4;
        int d4 = (fi & 15) * 4;
        float4 s = ((const float4*)Sp)[fi];
        *(float4*)&Ss[t][d4] = s;
    }
    if (tid < 64) zs[tid] = Sp[4096 + tid];
    __syncthreads();
    int r  = tid >> 2;
    int c0 = (tid & 3) * 16;
    float a[16];
#pragma unroll
    for (int i = 0; i < 16; i++) a[i] = 0.0f;
    for (int d = 0; d < 64; d++) {
        float q = Qs[r][d];
        const float4* kr = (const float4*)&Kt[d][c0];
        float4 k0 = kr[0], k1 = kr[1], k2 = kr[2], k3 = kr[3];
        a[0]+=q*k0.x; a[1]+=q*k0.y; a[2]+=q*k0.z; a[3]+=q*k0.w;
        a[4]+=q*k1.x; a[5]+=q*k1.y; a[6]+=q*k1.z; a[7]+=q*k1.w;
        a[8]+=q*k2.x; a[9]+=q*k2.y; a[10]+=q*k2.z; a[11]+=q*k2.w;
        a[12]+=q*k3.x; a[13]+=q*k3.y; a[14]+=q*k3.z; a[15]+=q*k3.w;
    }
    union { bf16x8 v8[2]; bf16 hh[16]; } ua;
#pragma unroll
    for (int i = 0; i < 16; i++) ua.hh[i] = __float2bfloat16(a[i]);
    *(bf16x8*)&Amat[r][c0]   = ua.v8[0];
    *(bf16x8*)&Amat[r][c0+8] = ua.v8[1];
    __syncthreads();
    float den = 0.0f;
    for (int d = 0; d < 64; d++) den += Qs[r][d] * zs[d];
    for (int j = 0; j <= r; j++) den += b2f(*(const short*)&Amat[r][j]);
    den = fmaxf(den, 1e-6f);
    float num[16];
#pragma unroll
    for (int i = 0; i < 16; i++) num[i] = 0.0f;
    for (int d = 0; d < 64; d++) {
        float q = Qs[r][d];
        const float4* sv = (const float4*)&Ss[d][c0];
        float4 s0 = sv[0], s1 = sv[1], s2 = sv[2], s3 = sv[3];
        num[0]+=q*s0.x; num[1]+=q*s0.y; num[2]+=q*s0.z; num[3]+=q*s0.w;
        num[4]+=q*s1.x; num[5]+=q*s1.y; num[6]+=q*s1.z; num[7]+=q*s1.w;
        num[8]+=q*s2.x; num[9]+=q*s2.y; num[10]+=q*s2.z; num[11]+=q*s2.w;
        num[12]+=q*s3.x; num[13]+=q*s3.y; num[14]+=q*s3.z; num[15]+=q*s3.w;
    }
    for (int j = 0; j <= r; j++) {
        float aj = b2f(*(const short*)&Amat[r][j]);
        const float4* vv = (const float4*)&Vs[j][c0];
        float4 v0 = vv[0], v1 = vv[1], v2 = vv[2], v3 = vv[3];
        num[0]+=aj*v0.x; num[1]+=aj*v0.y; num[2]+=aj*v0.z; num[3]+=aj*v0.w;
        num[4]+=aj*v1.x; num[5]+=aj*v1.y; num[6]+=aj*v1.z; num[7]+=aj*v1.w;
        num[8]+=aj*v2.x; num[9]+=aj*v2.y; num[10]+=aj*v2.z; num[11]+=aj*v2.w;
        num[12]+=aj*v3.x; num[13]+=aj*v3.y; num[14]+=aj*v3.z; num[15]+=aj*v3.w;
    }
    float inv = 1.0f / den;
    union { short4 s4[4]; bf16 hh[16]; } u;
#pragma unroll
    for (int i = 0; i < 16; i++) u.hh[i] = __float2bfloat16(num[i] * inv);
    short4* op = (short4*)(attnb + ((size_t)b * T_SEQ + ch*64 + r) * DM + h*64 + c0);
#pragma unroll
    for (int i = 0; i < 4; i++) op[i] = u.s4[i];
}

extern "C" void kernel_launch(void* const* d_in, const int* in_sizes, int n_in,
                              void* d_out, int out_size, void* d_ws, size_t ws_size,
                              hipStream_t stream)
{
    (void)in_sizes; (void)n_in; (void)out_size; (void)ws_size;
    const float* x     = (const float*)d_in[0];
    const float* ln1_g = (const float*)d_in[1];
    const float* ln1_b = (const float*)d_in[2];
    const float* Wq = (const float*)d_in[3];
    const float* bq = (const float*)d_in[4];
    const float* Wk = (const float*)d_in[5];
    const float* bk = (const float*)d_in[6];
    const float* Wv = (const float*)d_in[7];
    const float* bv = (const float*)d_in[8];
    const float* Wo = (const float*)d_in[9];
    const float* bo = (const float*)d_in[10];
    const float* ln2_g = (const float*)d_in[11];
    const float* ln2_b = (const float*)d_in[12];
    const float* W1 = (const float*)d_in[13];
    const float* b1 = (const float*)d_in[14];
    const float* W2 = (const float*)d_in[15];
    const float* b2 = (const float*)d_in[16];
    float* out = (float*)d_out;
    char* base = (char*)d_ws;
    const size_t MB = 1048576;

    bf16*  h_bf  = (bf16*)(base + 0);
    bf16*  h2_bf = (bf16*)(base + 4*MB);
    bf16*  attnb = (bf16*)(base + 8*MB);
    bf16*  QKVWT = (bf16*)(base + 12*MB);
    bf16*  WoT   = (bf16*)(base + 14*MB);
    bf16*  W1T   = (bf16*)(base + 15*MB);
    bf16*  W2T   = (bf16*)(base + 17*MB);
    bf16*  Qb    = (bf16*)(base + 20*MB);
    bf16*  Kb    = (bf16*)(base + 24*MB);
    bf16*  Vb    = (bf16*)(base + 28*MB);
    float* St    = (float*)(base + 32*MB);
    float* X2    = (float*)(base + 41*MB);
    bf16*  FF    = (bf16*)(base + 50*MB);

    wcvt_all<<<768, 256, 0, stream>>>(Wq, Wk, Wv, Wo, W1, W2,
                                      QKVWT, WoT, W1T, W2T);

    ln_kernel<false><<<MROWS, 128, 0, stream>>>(x, ln1_g, ln1_b, h_bf, nullptr, nullptr);

    // fused QKV: [4096,512] @ [512,1536] -> head-layout bf16 Q,K,V
    mfma_gemm<128,128,4,2,0><<<dim3(12, 32), 512, 0, stream>>>(
        h_bf, QKVWT, bq, bk, bv, nullptr, nullptr, Qb, Kb, Vb, nullptr,
        MROWS, 1536, 512);

    attn_chunk_sum<<<BHN*NCHUNK, 256, 0, stream>>>(Kb, Vb, St);
    attn_scan<<<dim3(17, BHN), 64, 0, stream>>>(St);
    attn_out_k<<<BHN*NCHUNK, 256, 0, stream>>>(Qb, Kb, Vb, St, attnb);

    // X2 = attn @ Wo + bo + x   (64x64 tiles -> 512 blocks)
    mfma_gemm<64,64,2,2,1><<<dim3(8, 64), 256, 0, stream>>>(
        attnb, WoT, bo, nullptr, nullptr, x, X2, nullptr, nullptr, nullptr, nullptr,
        MROWS, 512, 512);

    // ln2 + pre-init out = X2 + b2
    ln_kernel<true><<<MROWS, 128, 0, stream>>>(X2, ln2_g, ln2_b, h2_bf, b2, out);

    // FF = relu(h2 @ W1 + b1)  (bf16)
    mfma_gemm<128,128,4,2,2><<<dim3(16, 32), 512, 0, stream>>>(
        h2_bf, W1T, b1, nullptr, nullptr, nullptr, nullptr, nullptr, nullptr, nullptr, FF,
        MROWS, DFF, 512);

    // out += FF @ W2 (split-K=2, atomic fp32 add)
    mfma_gemm<128,64,2,2,3><<<dim3(8, 32, 2), 256, 0, stream>>>(
        FF, W2T, nullptr, nullptr, nullptr, nullptr, out, nullptr, nullptr, nullptr, nullptr,
        MROWS, 512, 2048);
}